// Round 4
// baseline (260.546 us; speedup 1.0000x reference)
//
#include <hip/hip_runtime.h>
#include <cstdint>
#include <cstddef>

#define DM 1024
#define NH 16
#define DKD 64
#define BB 4
#define SS 2048
#define MTOT (BB*SS)   // 8192 rows

typedef float  f32x4  __attribute__((ext_vector_type(4)));
typedef __bf16 bf16x8 __attribute__((ext_vector_type(8)));
typedef __bf16 bf16x4v __attribute__((ext_vector_type(4)));
typedef __bf16 bf16x2v __attribute__((ext_vector_type(2)));
using as3v = __attribute__((address_space(3))) void;
using as1v = __attribute__((address_space(1))) void;

__device__ __forceinline__ void gl2lds16(const void* g, void* l) {
  __builtin_amdgcn_global_load_lds((as1v*)g, (as3v*)l, 16, 0, 0);
}

__device__ __forceinline__ float fast_exp2(float x) {
#if __has_builtin(__builtin_amdgcn_exp2f)
  return __builtin_amdgcn_exp2f(x);
#else
  return __expf(x * 0.6931471805599453f);
#endif
}

// sin/cos with input in revolutions (v_sin_f32 semantics: D = sin(S*2pi))
__device__ __forceinline__ void sincos_rev(float rev, float* s, float* c) {
#if __has_builtin(__builtin_amdgcn_sinf) && __has_builtin(__builtin_amdgcn_cosf)
  *s = __builtin_amdgcn_sinf(rev);
  *c = __builtin_amdgcn_cosf(rev);
#else
  float a = rev * 6.283185307179586f;
  *s = __sinf(a); *c = __cosf(a);
#endif
}

// pack two f32 -> one u32 of 2 bf16 (compiler emits v_cvt_pk_bf16_f32)
__device__ __forceinline__ uint32_t pkbf(float a, float b) {
  union { uint32_t u; __bf16 h[2]; } c;
  c.h[0] = (__bf16)a; c.h[1] = (__bf16)b;
  return c.u;
}

// ---------------- fused cast fp32 -> bf16 for x + 4 weights ----------------
// WQ/WK rows are permuted per head: even feature d=2i -> i, odd d=2i+1 -> 32+i.
__global__ void cast_all_k(const float* __restrict__ x,
                           const float* __restrict__ wq, const float* __restrict__ wk,
                           const float* __restrict__ wv, const float* __restrict__ wo,
                           __bf16* __restrict__ xb,
                           __bf16* __restrict__ wqb, __bf16* __restrict__ wkb,
                           __bf16* __restrict__ wvb, __bf16* __restrict__ wob) {
  int i = blockIdx.x * blockDim.x + threadIdx.x;   // 3,145,728 float4 groups
  const float* src;
  __bf16* dst;
  int idx, oidx;
  if (i < 2097152) {          // x: 8M elems
    src = x; dst = xb; idx = i; oidx = i;
  } else {
    int j = i - 2097152;
    int w = j >> 18;          // 256K float4 per weight
    idx = j & 262143;
    src = (w == 0) ? wq : (w == 1) ? wk : (w == 2) ? wv : wo;
    dst = (w == 0) ? wqb : (w == 1) ? wkb : (w == 2) ? wvb : wob;
    if (w < 2) {
      int e = idx >> 8;            // output-feature row (1024 floats = 256 f4/row)
      int c = idx & 255;
      int d = e & 63;
      int dp = (d & 1) ? 32 + (d >> 1) : (d >> 1);
      oidx = (((e & ~63) | dp) << 8) | c;
    } else {
      oidx = idx;
    }
  }
  float4 f = ((const float4*)src)[idx];
  bf16x4v o;
  o[0] = (__bf16)f.x; o[1] = (__bf16)f.y; o[2] = (__bf16)f.z; o[3] = (__bf16)f.w;
  ((bf16x4v*)dst)[oidx] = o;
}

// ---------------- RoPE cos/sin table: tbl[s][i] = {cos,sin}(pos[s]*invf_i) --------
__global__ void rope_tbl_k(const int* __restrict__ pos, float2* __restrict__ tbl) {
  int p = blockIdx.x * blockDim.x + threadIdx.x;   // 2048*32
  int s = p >> 5;
  int i = p & 31;
  float ps = (float)pos[s];
  float invr = __expf(-0.28782313663f * (float)i) * 0.15915494309f;  // invf/(2pi)
  float rev = ps * invr;
  rev -= floorf(rev);
  float sn, cs;
  sincos_rev(rev, &sn, &cs);
  tbl[p] = make_float2(cs, sn);
}

// ======== shared GEMM K-loop pieces (v11) ========
// Content swizzle: LDS stays linear (global_load_lds constraint, rule #21);
// within each 128B pair-of-rows region (8 chunks of 16B), linear chunk cl holds
// the content of chunk cl ^ (pair&7). Applied on the global SOURCE address at
// staging and on the fragment-read address -> ds_read_b128 lands <=2-way on
// banks (free) instead of ~8-way.
// Pipeline: single barrier per K-step; stage(next buf) issued right after the
// barrier, compute(cur buf) underneath -> the next barrier's implicit vmcnt(0)
// drain finds the loads already landed (T3 2-phase minimum, proven in attn10).

// ---------------- GEMM: C[M,N] = A[M,K] * B[N,K]^T  (token-major C) ----------------
template <typename CT>
__global__ __launch_bounds__(256, 4) void gemm_bt_k(const __bf16* __restrict__ A,
                                                    const __bf16* __restrict__ B,
                                                    CT* __restrict__ C,
                                                    int M, int N, int K) {
  __shared__ __bf16 As[2][128 * 32];
  __shared__ __bf16 Bs[2][128 * 32];
  const int tid  = threadIdx.x;
  const int lane = tid & 63;
  const int wid  = tid >> 6;
  const int lrow = lane & 15;
  const int quad = lane >> 4;
  const int m0 = blockIdx.y * 128;
  const int n0 = blockIdx.x * 128;
  const int wm = (wid & 1) * 64;
  const int wn = (wid >> 1) * 64;

  // staging source (content-swizzled, loop-invariant)
  const int r0 = wid * 32 + (lane >> 2);
  const int cs = (((r0 & 1) << 2) | (lane & 3)) ^ ((r0 >> 1) & 7);
  const int gr = (r0 & ~1) | (cs >> 2);
  const int gc = cs & 3;
  const __bf16* Asrc = A + (size_t)(m0 + gr) * K + gc * 8;
  const __bf16* Bsrc = B + (size_t)(n0 + gr) * K + gc * 8;
  // fragment-read swizzled chunk (row-parity/quad XOR pair-index)
  const int clf = (((lrow & 1) << 2) + quad) ^ (lrow >> 1);

  f32x4 acc[4][4] = {};

  auto stage = [&](int buf, int k0) {
    gl2lds16(Asrc + k0,                   &As[buf][(wid * 32)      * 32]);
    gl2lds16(Asrc + (size_t)16 * K + k0,  &As[buf][(wid * 32 + 16) * 32]);
    gl2lds16(Bsrc + k0,                   &Bs[buf][(wid * 32)      * 32]);
    gl2lds16(Bsrc + (size_t)16 * K + k0,  &Bs[buf][(wid * 32 + 16) * 32]);
  };

  stage(0, 0);
  const int kiters = K >> 5;
  for (int kk = 0; kk < kiters; ++kk) {
    __syncthreads();                    // own vmcnt(0) drain + barrier: buf[kk&1] ready
    if (kk + 1 < kiters) stage((kk + 1) & 1, (kk + 1) * 32);
    const __bf16* as = As[kk & 1];
    const __bf16* bs = Bs[kk & 1];

    bf16x8 af[4], bfr[4];
#pragma unroll
    for (int i = 0; i < 4; ++i)
      af[i] = *(const bf16x8*)(as + ((wm + i * 16 + lrow) >> 1) * 64 + clf * 8);
#pragma unroll
    for (int i = 0; i < 4; ++i)
      bfr[i] = *(const bf16x8*)(bs + ((wn + i * 16 + lrow) >> 1) * 64 + clf * 8);
    __builtin_amdgcn_s_setprio(1);
#pragma unroll
    for (int mi = 0; mi < 4; ++mi)
#pragma unroll
      for (int ni = 0; ni < 4; ++ni)
        acc[mi][ni] = __builtin_amdgcn_mfma_f32_16x16x32_bf16(af[mi], bfr[ni], acc[mi][ni], 0, 0, 0);
    __builtin_amdgcn_s_setprio(0);
  }

#pragma unroll
  for (int mi = 0; mi < 4; ++mi)
#pragma unroll
    for (int ni = 0; ni < 4; ++ni)
#pragma unroll
      for (int r = 0; r < 4; ++r) {
        int row = m0 + wm + mi * 16 + quad * 4 + r;
        int col = n0 + wn + ni * 16 + lrow;
        C[(size_t)row * N + col] = (CT)acc[mi][ni][r];
      }
}

// ---------------- fused QKV GEMM + RoPE(Q,K, in-lane) + V-transpose ----------------
// V-store note (v9): VT's key axis is permuted within each 32-token block:
// position 8*quad + 4*(mi&1) + r  <-  original key (mi&1)*16 + quad*4 + r.
// This makes the attention PV A-fragment a direct pack of each lane's own
// QK^T outputs. Softmax is key-order invariant; causal mask untouched.
__global__ __launch_bounds__(256, 4) void gemm_qkv_k(const __bf16* __restrict__ A,
                                                     const __bf16* __restrict__ Bq,
                                                     const __bf16* __restrict__ Bk,
                                                     const __bf16* __restrict__ Bv,
                                                     const float2* __restrict__ tbl,
                                                     __bf16* __restrict__ Cq,
                                                     __bf16* __restrict__ Ck,
                                                     __bf16* __restrict__ Cv) {
  __shared__ __bf16 As[2][128 * 32];
  __shared__ __bf16 Bs[2][128 * 32];
  const int sel = blockIdx.x >> 3;
  const __bf16* B = sel == 0 ? Bq : sel == 1 ? Bk : Bv;
  const int n0 = (blockIdx.x & 7) * 128;
  const int m0 = blockIdx.y * 128;
  const int K = DM;
  const int tid  = threadIdx.x;
  const int lane = tid & 63;
  const int wid  = tid >> 6;
  const int lrow = lane & 15;
  const int quad = lane >> 4;
  const int wm = (wid & 1) * 64;
  const int wn = (wid >> 1) * 64;

  // staging source (content-swizzled, loop-invariant)
  const int r0 = wid * 32 + (lane >> 2);
  const int cs = (((r0 & 1) << 2) | (lane & 3)) ^ ((r0 >> 1) & 7);
  const int gr = (r0 & ~1) | (cs >> 2);
  const int gc = cs & 3;
  const __bf16* Asrc = A + (size_t)(m0 + gr) * K + gc * 8;
  const __bf16* Bsrc = B + (size_t)(n0 + gr) * K + gc * 8;
  const int clf = (((lrow & 1) << 2) + quad) ^ (lrow >> 1);

  f32x4 acc[4][4] = {};

  auto stage = [&](int buf, int k0) {
    gl2lds16(Asrc + k0,                   &As[buf][(wid * 32)      * 32]);
    gl2lds16(Asrc + (size_t)16 * K + k0,  &As[buf][(wid * 32 + 16) * 32]);
    gl2lds16(Bsrc + k0,                   &Bs[buf][(wid * 32)      * 32]);
    gl2lds16(Bsrc + (size_t)16 * K + k0,  &Bs[buf][(wid * 32 + 16) * 32]);
  };

  stage(0, 0);
  const int kiters = K >> 5;   // 32
  for (int kk = 0; kk < kiters; ++kk) {
    __syncthreads();
    if (kk + 1 < kiters) stage((kk + 1) & 1, (kk + 1) * 32);
    const __bf16* as = As[kk & 1];
    const __bf16* bs = Bs[kk & 1];

    bf16x8 af[4], bfr[4];
#pragma unroll
    for (int i = 0; i < 4; ++i)
      af[i] = *(const bf16x8*)(as + ((wm + i * 16 + lrow) >> 1) * 64 + clf * 8);
#pragma unroll
    for (int i = 0; i < 4; ++i)
      bfr[i] = *(const bf16x8*)(bs + ((wn + i * 16 + lrow) >> 1) * 64 + clf * 8);
    __builtin_amdgcn_s_setprio(1);
#pragma unroll
    for (int mi = 0; mi < 4; ++mi)
#pragma unroll
      for (int ni = 0; ni < 4; ++ni)
        acc[mi][ni] = __builtin_amdgcn_mfma_f32_16x16x32_bf16(af[mi], bfr[ni], acc[mi][ni], 0, 0, 0);
    __builtin_amdgcn_s_setprio(0);
  }

  const int hbase = (n0 + wn) >> 6;   // head index for this wave's 64-col block
  const int bq = m0 >> 11;            // batch (128-row tile never crosses batch)

  if (sel == 2) {
    // V: store transposed into VT [bh][64][s'], s' = within-32-block permuted key
    __bf16* vt = Cv + ((size_t)(bq * NH + hbase)) * (DKD * SS);
    const int S0 = (m0 + wm) & (SS - 1);          // multiple of 64
#pragma unroll
    for (int ni = 0; ni < 4; ++ni) {
      const int d = ni * 16 + lrow;
#pragma unroll
      for (int mi = 0; mi < 4; ++mi) {
        bf16x4v pk;
#pragma unroll
        for (int r = 0; r < 4; ++r) pk[r] = (__bf16)acc[mi][ni][r];
        const int sp = S0 + (mi >> 1) * 32 + quad * 8 + (mi & 1) * 4;  // permuted pos
        *(bf16x4v*)(vt + (size_t)d * SS + sp) = pk;
      }
    }
  } else {
    // Q or K: in-lane RoPE via table. Pair = (acc[.][ni], acc[.][ni+2]), i = ni*16+lrow.
    __bf16* C = ((sel == 0) ? Cq : Ck) + ((size_t)(bq * NH + hbase)) * (SS * DKD);
#pragma unroll
    for (int ni = 0; ni < 2; ++ni) {
      const int i = ni * 16 + lrow;                 // pair index 0..31
#pragma unroll
      for (int mi = 0; mi < 4; ++mi) {
#pragma unroll
        for (int r = 0; r < 4; ++r) {
          int s = (m0 + wm + mi * 16 + quad * 4 + r) & (SS - 1);
          float2 cssn = tbl[s * 32 + i];
          float a = acc[mi][ni][r];       // x1 (even feature of the pair)
          float b = acc[mi][ni + 2][r];   // x2 (odd feature)
          C[(size_t)s * DKD + i]      = (__bf16)fmaf(a, cssn.x, -(b * cssn.y)); // x1 c - x2 s
          C[(size_t)s * DKD + 32 + i] = (__bf16)fmaf(a, cssn.y,  (b * cssn.x)); // x1 s + x2 c
        }
      }
    }
  }
}

// ---------------- attention v10: paired q-tiles, perfectly balanced blocks ----------
//  One block = q-tile pair (pr, 15-pr) -> every block runs EXACTLY 17 key-tile
//  iterations; 512 blocks = 2/CU, single round, zero tail. Double-buffer
//  pipeline carries across the segment boundary.
__global__ __launch_bounds__(512, 4) void attn10_k(const __bf16* __restrict__ Qh,
                                                   const __bf16* __restrict__ Kh,
                                                   const __bf16* __restrict__ VT,
                                                   __bf16* __restrict__ O) {
  __shared__ __bf16 Ks[2][128 * 64];   // swizzled [key][chunk8], double-buffered
  __shared__ __bf16 Vt[2][64 * 128];   // swizzled [dk][chunk8 of 16], double-buffered
  const int tid  = threadIdx.x;
  const int lane = tid & 63;
  const int wid  = tid >> 6;           // 0..7
  const int lrow = lane & 15;
  const int quad = lane >> 4;
  const int j   = blockIdx.x;          // 0..511
  const int xcd = j & 7;
  const int t   = j >> 3;              // 0..63
  const int bh  = (xcd << 3) | (t >> 3);
  const int pr  = t & 7;
  const int qa  = pr;                  // segment-0 q-tile (qa+1 key-tiles)
  const int qb  = 15 - pr;             // segment-1 q-tile (16-pr key-tiles); total 17
  const int na  = qa + 1;
  const int b  = bh >> 4;
  const int h  = bh & 15;
  const size_t hb = (size_t)bh * (SS * DKD);

  const int skr = lane >> 3;   // K staging: row-local 0..7
  const int skc = lane & 7;    //            chunk 0..7
  const int svd = lane >> 4;   // V staging: dk-local 0..3
  const int svc = lane & 15;   //            chunk 0..15

  auto stage = [&](int kt, int bsel) {
#pragma unroll
    for (int ii = 0; ii < 2; ++ii) {
      int i = wid * 2 + ii;          // 0..15
      int key = i * 8 + skr;
      int gc = skc ^ (key & 7);
      gl2lds16(Kh + hb + (size_t)(kt * 128 + key) * DKD + gc * 8, &Ks[bsel][i * 512]);
      int dk = i * 4 + svd;
      int gc2 = (svc & 8) | ((svc ^ dk) & 7);
      gl2lds16(VT + hb + (size_t)dk * SS + kt * 128 + gc2 * 8, &Vt[bsel][i * 512]);
    }
  };

  // prologue: key-tile 0 (segment 0) in flight
  stage(0, 0);
  int it = 0;   // global iteration index 0..16; LDS buffer parity = it & 1

  for (int seg = 0; seg < 2; ++seg) {
    const int qi  = seg ? qb : qa;
    const int q0  = qi * 128;
    const int nkt = qi + 1;
    const int qg  = q0 + wid * 16 + lrow;  // this lane's q-row (col of S^T)

    bf16x8 qf0, qf1;
    {
      const __bf16* qp = Qh + hb + (size_t)qg * DKD + quad * 8;
      qf0 = *(const bf16x8*)qp;
      qf1 = *(const bf16x8*)(qp + 32);
    }
    f32x4 Oa[4] = {};
    float la = 0.f, lb = 0.f;   // split l-chain (serial fp adds not reassociable)

    for (int kt = 0; kt < nkt; ++kt, ++it) {
      __syncthreads();
      {
        int nit = it + 1;
        if (nit < 17) {
          int nk = (nit < na) ? nit : (nit - na);   // next key-tile (crosses segs)
          stage(nk, nit & 1);
        }
      }
      const __bf16* ks = Ks[it & 1];
      const __bf16* vt = Vt[it & 1];

      // S^T = K * Q^T : A = K-frag (m=key), B = Q-frag (n=q)
      f32x4 sa[8];
#pragma unroll
      for (int mi = 0; mi < 8; ++mi) sa[mi] = (f32x4){0.f, 0.f, 0.f, 0.f};
      __builtin_amdgcn_s_setprio(1);
#pragma unroll
      for (int tt = 0; tt < 2; ++tt) {
        bf16x8 qf = tt ? qf1 : qf0;
#pragma unroll
        for (int mi = 0; mi < 8; ++mi) {
          bf16x8 kf = *(const bf16x8*)(ks + (mi * 16 + lrow) * 64 + (((tt * 4 + quad) ^ (lrow & 7)) * 8));
          sa[mi] = __builtin_amdgcn_mfma_f32_16x16x32_bf16(kf, qf, sa[mi], 0, 0, 0);
        }
      }
      __builtin_amdgcn_s_setprio(0);

      // fused softmax + direct pack + PV, per 32-key block kc.
      const bool lastt = (kt == nkt - 1);
#pragma unroll
      for (int kc = 0; kc < 4; ++kc) {
        union { uint32_t u[4]; bf16x8 v; } P;
#pragma unroll
        for (int half = 0; half < 2; ++half) {
          const int mi = kc * 2 + half;
          float pr4[4];
#pragma unroll
          for (int r = 0; r < 4; ++r) {
            float p = fast_exp2(sa[mi][r] * 0.18033688f - 8.0f);
            if (lastt) {
              int key = kt * 128 + kc * 32 + half * 16 + quad * 4 + r;
              p = (key <= qg) ? p : 0.f;
            }
            pr4[r] = p;
          }
          float s01 = pr4[0] + pr4[1];
          float s23 = pr4[2] + pr4[3];
          if (half) lb += (s01 + s23); else la += (s01 + s23);
          P.u[half * 2]     = pkbf(pr4[0], pr4[1]);
          P.u[half * 2 + 1] = pkbf(pr4[2], pr4[3]);
        }
        __builtin_amdgcn_s_setprio(1);
#pragma unroll
        for (int ni = 0; ni < 4; ++ni) {
          int c = kc * 4 + quad;
          int cp = (c & 8) | ((c ^ (lrow & 7)) & 7);
          bf16x8 vf = *(const bf16x8*)(vt + (ni * 16 + lrow) * 128 + cp * 8);
          Oa[ni] = __builtin_amdgcn_mfma_f32_16x16x32_bf16(P.v, vf, Oa[ni], 0, 0, 0);
        }
        __builtin_amdgcn_s_setprio(0);
      }
    }

    // per-segment epilogue: l reduction across quads, normalize, store
    float l = la + lb;
    l += __shfl_xor(l, 16, 64);
    l += __shfl_xor(l, 32, 64);
#pragma unroll
    for (int r = 0; r < 4; ++r) {
      float li = __shfl(l, quad * 4 + r, 64);   // l for q-row quad*4+r
      float inv = 1.0f / li;
      int row = q0 + wid * 16 + quad * 4 + r;
#pragma unroll
      for (int ni = 0; ni < 4; ++ni)
        O[(size_t)b * SS * DM + (size_t)row * DM + h * DKD + ni * 16 + lrow] =
            (__bf16)(Oa[ni][r] * inv);
    }
  }
}

// ---------------- launch ----------------
extern "C" void kernel_launch(void* const* d_in, const int* in_sizes, int n_in,
                              void* d_out, int out_size, void* d_ws, size_t ws_size,
                              hipStream_t stream) {
  (void)in_sizes; (void)n_in; (void)out_size; (void)ws_size;
  const float* x  = (const float*)d_in[0];
  const int*   pos = (const int*)d_in[1];
  const float* WQ = (const float*)d_in[2];
  const float* WK = (const float*)d_in[3];
  const float* WV = (const float*)d_in[4];
  const float* WO = (const float*)d_in[5];
  float* out = (float*)d_out;

  char* w = (char*)d_ws;
  const size_t MB = 1024 * 1024;
  __bf16* xb  = (__bf16*)(w);             // 16 MB
  __bf16* wqb = (__bf16*)(w + 16 * MB);   // permuted rows
  __bf16* wkb = (__bf16*)(w + 18 * MB);   // permuted rows
  __bf16* wvb = (__bf16*)(w + 20 * MB);
  __bf16* wob = (__bf16*)(w + 22 * MB);
  __bf16* Qh  = (__bf16*)(w + 24 * MB);   // head-major [bh][s][64], RoPE'd (permuted d)
  __bf16* Kh  = (__bf16*)(w + 40 * MB);   // head-major [bh][s][64], RoPE'd (permuted d)
  __bf16* Cb  = (__bf16*)(w + 56 * MB);   // context token-major
  __bf16* VT  = (__bf16*)(w + 72 * MB);   // [bh][64][s'], key-permuted within 32-blocks
  float2* tbl = (float2*)(w + 88 * MB);   // rope table, 512 KB

  // fused cast: x + 4 weights -> bf16 (WQ/WK rows permuted per head)
  cast_all_k<<<3145728 / 256, 256, 0, stream>>>(x, WQ, WK, WV, WO, xb, wqb, wkb, wvb, wob);

  // rope cos/sin table
  rope_tbl_k<<<(SS * 32) / 256, 256, 0, stream>>>(pos, tbl);

  // fused QKV projection + in-lane RoPE(Q,K) + V-transpose (key-permuted)
  gemm_qkv_k<<<dim3(24, MTOT / 128), 256, 0, stream>>>(xb, wqb, wkb, wvb, tbl, Qh, Kh, VT);

  // attention -> context (token-major); 512 perfectly-balanced blocks
  attn10_k<<<dim3(512), 512, 0, stream>>>(Qh, Kh, VT, Cb);

  // output projection (fp32 out)
  gemm_bt_k<float><<<dim3(DM / 128, MTOT / 128), 256, 0, stream>>>(Cb, wob, out, MTOT, DM, DM);
}

// Round 6
// 250.489 us; speedup vs baseline: 1.0402x; 1.0402x over previous
//
#include <hip/hip_runtime.h>
#include <cstdint>
#include <cstddef>

#define DM 1024
#define NH 16
#define DKD 64
#define BB 4
#define SS 2048
#define MTOT (BB*SS)   // 8192 rows

typedef float  f32x4  __attribute__((ext_vector_type(4)));
typedef __bf16 bf16x8 __attribute__((ext_vector_type(8)));
typedef __bf16 bf16x4v __attribute__((ext_vector_type(4)));
typedef __bf16 bf16x2v __attribute__((ext_vector_type(2)));
using as3v = __attribute__((address_space(3))) void;
using as1v = __attribute__((address_space(1))) void;

__device__ __forceinline__ void gl2lds16(const void* g, void* l) {
  __builtin_amdgcn_global_load_lds((as1v*)g, (as3v*)l, 16, 0, 0);
}

// raw barrier with compiler memory fence (NOT __syncthreads: that drains vmcnt(0))
#define BAR() asm volatile("s_barrier" ::: "memory")
#define WAITV(NSTR) asm volatile("s_waitcnt vmcnt(" NSTR ")" ::: "memory")
#define SCHEDB() __builtin_amdgcn_sched_barrier(0)

__device__ __forceinline__ float fast_exp2(float x) {
#if __has_builtin(__builtin_amdgcn_exp2f)
  return __builtin_amdgcn_exp2f(x);
#else
  return __expf(x * 0.6931471805599453f);
#endif
}

// sin/cos with input in revolutions (v_sin_f32 semantics: D = sin(S*2pi))
__device__ __forceinline__ void sincos_rev(float rev, float* s, float* c) {
#if __has_builtin(__builtin_amdgcn_sinf) && __has_builtin(__builtin_amdgcn_cosf)
  *s = __builtin_amdgcn_sinf(rev);
  *c = __builtin_amdgcn_cosf(rev);
#else
  float a = rev * 6.283185307179586f;
  *s = __sinf(a); *c = __cosf(a);
#endif
}

// pack two f32 -> one u32 of 2 bf16 (compiler emits v_cvt_pk_bf16_f32)
__device__ __forceinline__ uint32_t pkbf(float a, float b) {
  union { uint32_t u; __bf16 h[2]; } c;
  c.h[0] = (__bf16)a; c.h[1] = (__bf16)b;
  return c.u;
}

// ---------------- fused cast fp32 -> bf16 for x + 4 weights ----------------
// WQ/WK rows are permuted per head: even feature d=2i -> i, odd d=2i+1 -> 32+i.
__global__ void cast_all_k(const float* __restrict__ x,
                           const float* __restrict__ wq, const float* __restrict__ wk,
                           const float* __restrict__ wv, const float* __restrict__ wo,
                           __bf16* __restrict__ xb,
                           __bf16* __restrict__ wqb, __bf16* __restrict__ wkb,
                           __bf16* __restrict__ wvb, __bf16* __restrict__ wob) {
  int i = blockIdx.x * blockDim.x + threadIdx.x;   // 3,145,728 float4 groups
  const float* src;
  __bf16* dst;
  int idx, oidx;
  if (i < 2097152) {          // x: 8M elems
    src = x; dst = xb; idx = i; oidx = i;
  } else {
    int j = i - 2097152;
    int w = j >> 18;          // 256K float4 per weight
    idx = j & 262143;
    src = (w == 0) ? wq : (w == 1) ? wk : (w == 2) ? wv : wo;
    dst = (w == 0) ? wqb : (w == 1) ? wkb : (w == 2) ? wvb : wob;
    if (w < 2) {
      int e = idx >> 8;            // output-feature row (1024 floats = 256 f4/row)
      int c = idx & 255;
      int d = e & 63;
      int dp = (d & 1) ? 32 + (d >> 1) : (d >> 1);
      oidx = (((e & ~63) | dp) << 8) | c;
    } else {
      oidx = idx;
    }
  }
  float4 f = ((const float4*)src)[idx];
  bf16x4v o;
  o[0] = (__bf16)f.x; o[1] = (__bf16)f.y; o[2] = (__bf16)f.z; o[3] = (__bf16)f.w;
  ((bf16x4v*)dst)[oidx] = o;
}

// ---------------- RoPE cos/sin table: tbl[s][i] = {cos,sin}(pos[s]*invf_i) --------
__global__ void rope_tbl_k(const int* __restrict__ pos, float2* __restrict__ tbl) {
  int p = blockIdx.x * blockDim.x + threadIdx.x;   // 2048*32
  int s = p >> 5;
  int i = p & 31;
  float ps = (float)pos[s];
  float invr = __expf(-0.28782313663f * (float)i) * 0.15915494309f;  // invf/(2pi)
  float rev = ps * invr;
  rev -= floorf(rev);
  float sn, cs;
  sincos_rev(rev, &sn, &cs);
  tbl[p] = make_float2(cs, sn);
}

// ======== shared GEMM K-loop pieces (v12b, re-run of v12 after container failure) ====
// Content swizzle (v11, verified: SQ_LDS_BANK_CONFLICT = 0): LDS stays linear
// (global_load_lds constraint, rule #21); within each 128B pair-of-rows region
// chunk cl holds content of chunk cl ^ (pair&7); applied on the global SOURCE
// at staging and on the fragment-read address.
// Pipeline (T3/T4 derived waits): 4 LDS buffers, stage kt+3 during kt,
// raw s_barrier + counted vmcnt (8 in steady state, 4/0 peeled at the tail,
// NEVER 0 in the main loop). At kt's closing barrier, kt+1's 4 loads are the
// oldest in flight with 8 younger (kt+2, kt+3) -> vmcnt(8) retires them; the
// barrier publishes (vmcnt decrement => the LDS write landed). WAR: stage(kt+3)
// overwrites buf[(kt-1)&3], whose readers all retired before kt-1's closing
// barrier. sched_barrier(0) after each wait+barrier pins compiler motion.

// ---------------- GEMM: C[M,N] = A[M,K] * B[N,K]^T  (token-major C) ----------------
template <typename CT>
__global__ __launch_bounds__(256, 2) void gemm_bt_k(const __bf16* __restrict__ A,
                                                    const __bf16* __restrict__ B,
                                                    CT* __restrict__ C,
                                                    int M, int N, int K) {
  __shared__ __bf16 As[4][128 * 32];
  __shared__ __bf16 Bs[4][128 * 32];
  const int tid  = threadIdx.x;
  const int lane = tid & 63;
  const int wid  = tid >> 6;
  const int lrow = lane & 15;
  const int quad = lane >> 4;
  const int m0 = blockIdx.y * 128;
  const int n0 = blockIdx.x * 128;
  const int wm = (wid & 1) * 64;
  const int wn = (wid >> 1) * 64;

  // staging source (content-swizzled, loop-invariant)
  const int r0 = wid * 32 + (lane >> 2);
  const int cs = (((r0 & 1) << 2) | (lane & 3)) ^ ((r0 >> 1) & 7);
  const int gr = (r0 & ~1) | (cs >> 2);
  const int gc = cs & 3;
  const __bf16* Asrc = A + (size_t)(m0 + gr) * K + gc * 8;
  const __bf16* Bsrc = B + (size_t)(n0 + gr) * K + gc * 8;
  // fragment-read swizzled chunk (row-parity/quad XOR pair-index)
  const int clf = (((lrow & 1) << 2) + quad) ^ (lrow >> 1);

  f32x4 acc[4][4] = {};

  auto stage = [&](int kt) {
    const int buf = kt & 3;
    const int k0 = kt * 32;
    gl2lds16(Asrc + k0,                   &As[buf][(wid * 32)      * 32]);
    gl2lds16(Asrc + (size_t)16 * K + k0,  &As[buf][(wid * 32 + 16) * 32]);
    gl2lds16(Bsrc + k0,                   &Bs[buf][(wid * 32)      * 32]);
    gl2lds16(Bsrc + (size_t)16 * K + k0,  &Bs[buf][(wid * 32 + 16) * 32]);
  };

  auto kstep = [&](int kt, bool dostage) {
    if (dostage) stage(kt + 3);
    const __bf16* as = As[kt & 3];
    const __bf16* bs = Bs[kt & 3];
    bf16x8 af[4], bfr[4];
#pragma unroll
    for (int i = 0; i < 4; ++i)
      af[i] = *(const bf16x8*)(as + ((wm + i * 16 + lrow) >> 1) * 64 + clf * 8);
#pragma unroll
    for (int i = 0; i < 4; ++i)
      bfr[i] = *(const bf16x8*)(bs + ((wn + i * 16 + lrow) >> 1) * 64 + clf * 8);
    __builtin_amdgcn_s_setprio(1);
#pragma unroll
    for (int mi = 0; mi < 4; ++mi)
#pragma unroll
      for (int ni = 0; ni < 4; ++ni)
        acc[mi][ni] = __builtin_amdgcn_mfma_f32_16x16x32_bf16(af[mi], bfr[ni], acc[mi][ni], 0, 0, 0);
    __builtin_amdgcn_s_setprio(0);
  };

  const int kiters = K >> 5;   // 32
  stage(0); stage(1); stage(2);
  WAITV("8"); BAR(); SCHEDB(); // tile 0's 4 loads retired (8 younger in flight)
  for (int kt = 0; kt < kiters - 3; ++kt) {
    kstep(kt, true);
    WAITV("8"); BAR(); SCHEDB();   // kt+1 retired; publish
  }
  kstep(kiters - 3, false); WAITV("4"); BAR(); SCHEDB();
  kstep(kiters - 2, false); WAITV("0"); BAR(); SCHEDB();
  kstep(kiters - 1, false);

#pragma unroll
  for (int mi = 0; mi < 4; ++mi)
#pragma unroll
    for (int ni = 0; ni < 4; ++ni)
#pragma unroll
      for (int r = 0; r < 4; ++r) {
        int row = m0 + wm + mi * 16 + quad * 4 + r;
        int col = n0 + wn + ni * 16 + lrow;
        C[(size_t)row * N + col] = (CT)acc[mi][ni][r];
      }
}

// ---------------- fused QKV GEMM + RoPE(Q,K, in-lane) + V-transpose ----------------
// V-store note (v9): VT's key axis is permuted within each 32-token block:
// position 8*quad + 4*(mi&1) + r  <-  original key (mi&1)*16 + quad*4 + r.
// This makes the attention PV A-fragment a direct pack of each lane's own
// QK^T outputs. Softmax is key-order invariant; causal mask untouched.
__global__ __launch_bounds__(256, 2) void gemm_qkv_k(const __bf16* __restrict__ A,
                                                     const __bf16* __restrict__ Bq,
                                                     const __bf16* __restrict__ Bk,
                                                     const __bf16* __restrict__ Bv,
                                                     const float2* __restrict__ tbl,
                                                     __bf16* __restrict__ Cq,
                                                     __bf16* __restrict__ Ck,
                                                     __bf16* __restrict__ Cv) {
  __shared__ __bf16 As[4][128 * 32];
  __shared__ __bf16 Bs[4][128 * 32];
  const int sel = blockIdx.x >> 3;
  const __bf16* B = sel == 0 ? Bq : sel == 1 ? Bk : Bv;
  const int n0 = (blockIdx.x & 7) * 128;
  const int m0 = blockIdx.y * 128;
  const int K = DM;
  const int tid  = threadIdx.x;
  const int lane = tid & 63;
  const int wid  = tid >> 6;
  const int lrow = lane & 15;
  const int quad = lane >> 4;
  const int wm = (wid & 1) * 64;
  const int wn = (wid >> 1) * 64;

  // staging source (content-swizzled, loop-invariant)
  const int r0 = wid * 32 + (lane >> 2);
  const int cs = (((r0 & 1) << 2) | (lane & 3)) ^ ((r0 >> 1) & 7);
  const int gr = (r0 & ~1) | (cs >> 2);
  const int gc = cs & 3;
  const __bf16* Asrc = A + (size_t)(m0 + gr) * K + gc * 8;
  const __bf16* Bsrc = B + (size_t)(n0 + gr) * K + gc * 8;
  const int clf = (((lrow & 1) << 2) + quad) ^ (lrow >> 1);

  f32x4 acc[4][4] = {};

  auto stage = [&](int kt) {
    const int buf = kt & 3;
    const int k0 = kt * 32;
    gl2lds16(Asrc + k0,                   &As[buf][(wid * 32)      * 32]);
    gl2lds16(Asrc + (size_t)16 * K + k0,  &As[buf][(wid * 32 + 16) * 32]);
    gl2lds16(Bsrc + k0,                   &Bs[buf][(wid * 32)      * 32]);
    gl2lds16(Bsrc + (size_t)16 * K + k0,  &Bs[buf][(wid * 32 + 16) * 32]);
  };

  auto kstep = [&](int kt, bool dostage) {
    if (dostage) stage(kt + 3);
    const __bf16* as = As[kt & 3];
    const __bf16* bs = Bs[kt & 3];
    bf16x8 af[4], bfr[4];
#pragma unroll
    for (int i = 0; i < 4; ++i)
      af[i] = *(const bf16x8*)(as + ((wm + i * 16 + lrow) >> 1) * 64 + clf * 8);
#pragma unroll
    for (int i = 0; i < 4; ++i)
      bfr[i] = *(const bf16x8*)(bs + ((wn + i * 16 + lrow) >> 1) * 64 + clf * 8);
    __builtin_amdgcn_s_setprio(1);
#pragma unroll
    for (int mi = 0; mi < 4; ++mi)
#pragma unroll
      for (int ni = 0; ni < 4; ++ni)
        acc[mi][ni] = __builtin_amdgcn_mfma_f32_16x16x32_bf16(af[mi], bfr[ni], acc[mi][ni], 0, 0, 0);
    __builtin_amdgcn_s_setprio(0);
  };

  const int kiters = K >> 5;   // 32
  stage(0); stage(1); stage(2);
  WAITV("8"); BAR(); SCHEDB();
  for (int kt = 0; kt < kiters - 3; ++kt) {
    kstep(kt, true);
    WAITV("8"); BAR(); SCHEDB();
  }
  kstep(kiters - 3, false); WAITV("4"); BAR(); SCHEDB();
  kstep(kiters - 2, false); WAITV("0"); BAR(); SCHEDB();
  kstep(kiters - 1, false);

  const int hbase = (n0 + wn) >> 6;   // head index for this wave's 64-col block
  const int bq = m0 >> 11;            // batch (128-row tile never crosses batch)

  if (sel == 2) {
    // V: store transposed into VT [bh][64][s'], s' = within-32-block permuted key
    __bf16* vt = Cv + ((size_t)(bq * NH + hbase)) * (DKD * SS);
    const int S0 = (m0 + wm) & (SS - 1);          // multiple of 64
#pragma unroll
    for (int ni = 0; ni < 4; ++ni) {
      const int d = ni * 16 + lrow;
#pragma unroll
      for (int mi = 0; mi < 4; ++mi) {
        bf16x4v pk;
#pragma unroll
        for (int r = 0; r < 4; ++r) pk[r] = (__bf16)acc[mi][ni][r];
        const int sp = S0 + (mi >> 1) * 32 + quad * 8 + (mi & 1) * 4;  // permuted pos
        *(bf16x4v*)(vt + (size_t)d * SS + sp) = pk;
      }
    }
  } else {
    // Q or K: in-lane RoPE via table. Pair = (acc[.][ni], acc[.][ni+2]), i = ni*16+lrow.
    __bf16* C = ((sel == 0) ? Cq : Ck) + ((size_t)(bq * NH + hbase)) * (SS * DKD);
#pragma unroll
    for (int ni = 0; ni < 2; ++ni) {
      const int i = ni * 16 + lrow;                 // pair index 0..31
#pragma unroll
      for (int mi = 0; mi < 4; ++mi) {
#pragma unroll
        for (int r = 0; r < 4; ++r) {
          int s = (m0 + wm + mi * 16 + quad * 4 + r) & (SS - 1);
          float2 cssn = tbl[s * 32 + i];
          float a = acc[mi][ni][r];       // x1 (even feature of the pair)
          float b = acc[mi][ni + 2][r];   // x2 (odd feature)
          C[(size_t)s * DKD + i]      = (__bf16)fmaf(a, cssn.x, -(b * cssn.y)); // x1 c - x2 s
          C[(size_t)s * DKD + 32 + i] = (__bf16)fmaf(a, cssn.y,  (b * cssn.x)); // x1 s + x2 c
        }
      }
    }
  }
}

// ---------------- attention v10: paired q-tiles, perfectly balanced blocks ----------
//  One block = q-tile pair (pr, 15-pr) -> every block runs EXACTLY 17 key-tile
//  iterations; 512 blocks = 2/CU, single round, zero tail. Double-buffer
//  pipeline carries across the segment boundary.
__global__ __launch_bounds__(512, 4) void attn10_k(const __bf16* __restrict__ Qh,
                                                   const __bf16* __restrict__ Kh,
                                                   const __bf16* __restrict__ VT,
                                                   __bf16* __restrict__ O) {
  __shared__ __bf16 Ks[2][128 * 64];   // swizzled [key][chunk8], double-buffered
  __shared__ __bf16 Vt[2][64 * 128];   // swizzled [dk][chunk8 of 16], double-buffered
  const int tid  = threadIdx.x;
  const int lane = tid & 63;
  const int wid  = tid >> 6;           // 0..7
  const int lrow = lane & 15;
  const int quad = lane >> 4;
  const int j   = blockIdx.x;          // 0..511
  const int xcd = j & 7;
  const int t   = j >> 3;              // 0..63
  const int bh  = (xcd << 3) | (t >> 3);
  const int pr  = t & 7;
  const int qa  = pr;                  // segment-0 q-tile (qa+1 key-tiles)
  const int qb  = 15 - pr;             // segment-1 q-tile (16-pr key-tiles); total 17
  const int na  = qa + 1;
  const int b  = bh >> 4;
  const int h  = bh & 15;
  const size_t hb = (size_t)bh * (SS * DKD);

  const int skr = lane >> 3;   // K staging: row-local 0..7
  const int skc = lane & 7;    //            chunk 0..7
  const int svd = lane >> 4;   // V staging: dk-local 0..3
  const int svc = lane & 15;   //            chunk 0..15

  auto stage = [&](int kt, int bsel) {
#pragma unroll
    for (int ii = 0; ii < 2; ++ii) {
      int i = wid * 2 + ii;          // 0..15
      int key = i * 8 + skr;
      int gc = skc ^ (key & 7);
      gl2lds16(Kh + hb + (size_t)(kt * 128 + key) * DKD + gc * 8, &Ks[bsel][i * 512]);
      int dk = i * 4 + svd;
      int gc2 = (svc & 8) | ((svc ^ dk) & 7);
      gl2lds16(VT + hb + (size_t)dk * SS + kt * 128 + gc2 * 8, &Vt[bsel][i * 512]);
    }
  };

  // prologue: key-tile 0 (segment 0) in flight
  stage(0, 0);
  int it = 0;   // global iteration index 0..16; LDS buffer parity = it & 1

  for (int seg = 0; seg < 2; ++seg) {
    const int qi  = seg ? qb : qa;
    const int q0  = qi * 128;
    const int nkt = qi + 1;
    const int qg  = q0 + wid * 16 + lrow;  // this lane's q-row (col of S^T)

    bf16x8 qf0, qf1;
    {
      const __bf16* qp = Qh + hb + (size_t)qg * DKD + quad * 8;
      qf0 = *(const bf16x8*)qp;
      qf1 = *(const bf16x8*)(qp + 32);
    }
    f32x4 Oa[4] = {};
    float la = 0.f, lb = 0.f;   // split l-chain (serial fp adds not reassociable)

    for (int kt = 0; kt < nkt; ++kt, ++it) {
      __syncthreads();
      {
        int nit = it + 1;
        if (nit < 17) {
          int nk = (nit < na) ? nit : (nit - na);   // next key-tile (crosses segs)
          stage(nk, nit & 1);
        }
      }
      const __bf16* ks = Ks[it & 1];
      const __bf16* vt = Vt[it & 1];

      // S^T = K * Q^T : A = K-frag (m=key), B = Q-frag (n=q)
      f32x4 sa[8];
#pragma unroll
      for (int mi = 0; mi < 8; ++mi) sa[mi] = (f32x4){0.f, 0.f, 0.f, 0.f};
      __builtin_amdgcn_s_setprio(1);
#pragma unroll
      for (int tt = 0; tt < 2; ++tt) {
        bf16x8 qf = tt ? qf1 : qf0;
#pragma unroll
        for (int mi = 0; mi < 8; ++mi) {
          bf16x8 kf = *(const bf16x8*)(ks + (mi * 16 + lrow) * 64 + (((tt * 4 + quad) ^ (lrow & 7)) * 8));
          sa[mi] = __builtin_amdgcn_mfma_f32_16x16x32_bf16(kf, qf, sa[mi], 0, 0, 0);
        }
      }
      __builtin_amdgcn_s_setprio(0);

      // fused softmax + direct pack + PV, per 32-key block kc.
      const bool lastt = (kt == nkt - 1);
#pragma unroll
      for (int kc = 0; kc < 4; ++kc) {
        union { uint32_t u[4]; bf16x8 v; } P;
#pragma unroll
        for (int half = 0; half < 2; ++half) {
          const int mi = kc * 2 + half;
          float pr4[4];
#pragma unroll
          for (int r = 0; r < 4; ++r) {
            float p = fast_exp2(sa[mi][r] * 0.18033688f - 8.0f);
            if (lastt) {
              int key = kt * 128 + kc * 32 + half * 16 + quad * 4 + r;
              p = (key <= qg) ? p : 0.f;
            }
            pr4[r] = p;
          }
          float s01 = pr4[0] + pr4[1];
          float s23 = pr4[2] + pr4[3];
          if (half) lb += (s01 + s23); else la += (s01 + s23);
          P.u[half * 2]     = pkbf(pr4[0], pr4[1]);
          P.u[half * 2 + 1] = pkbf(pr4[2], pr4[3]);
        }
        __builtin_amdgcn_s_setprio(1);
#pragma unroll
        for (int ni = 0; ni < 4; ++ni) {
          int c = kc * 4 + quad;
          int cp = (c & 8) | ((c ^ (lrow & 7)) & 7);
          bf16x8 vf = *(const bf16x8*)(vt + (ni * 16 + lrow) * 128 + cp * 8);
          Oa[ni] = __builtin_amdgcn_mfma_f32_16x16x32_bf16(P.v, vf, Oa[ni], 0, 0, 0);
        }
        __builtin_amdgcn_s_setprio(0);
      }
    }

    // per-segment epilogue: l reduction across quads, normalize, store
    float l = la + lb;
    l += __shfl_xor(l, 16, 64);
    l += __shfl_xor(l, 32, 64);
#pragma unroll
    for (int r = 0; r < 4; ++r) {
      float li = __shfl(l, quad * 4 + r, 64);   // l for q-row quad*4+r
      float inv = 1.0f / li;
      int row = q0 + wid * 16 + quad * 4 + r;
#pragma unroll
      for (int ni = 0; ni < 4; ++ni)
        O[(size_t)b * SS * DM + (size_t)row * DM + h * DKD + ni * 16 + lrow] =
            (__bf16)(Oa[ni][r] * inv);
    }
  }
}

// ---------------- launch ----------------
extern "C" void kernel_launch(void* const* d_in, const int* in_sizes, int n_in,
                              void* d_out, int out_size, void* d_ws, size_t ws_size,
                              hipStream_t stream) {
  (void)in_sizes; (void)n_in; (void)out_size; (void)ws_size;
  const float* x  = (const float*)d_in[0];
  const int*   pos = (const int*)d_in[1];
  const float* WQ = (const float*)d_in[2];
  const float* WK = (const float*)d_in[3];
  const float* WV = (const float*)d_in[4];
  const float* WO = (const float*)d_in[5];
  float* out = (float*)d_out;

  char* w = (char*)d_ws;
  const size_t MB = 1024 * 1024;
  __bf16* xb  = (__bf16*)(w);             // 16 MB
  __bf16* wqb = (__bf16*)(w + 16 * MB);   // permuted rows
  __bf16* wkb = (__bf16*)(w + 18 * MB);   // permuted rows
  __bf16* wvb = (__bf16*)(w + 20 * MB);
  __bf16* wob = (__bf16*)(w + 22 * MB);
  __bf16* Qh  = (__bf16*)(w + 24 * MB);   // head-major [bh][s][64], RoPE'd (permuted d)
  __bf16* Kh  = (__bf16*)(w + 40 * MB);   // head-major [bh][s][64], RoPE'd (permuted d)
  __bf16* Cb  = (__bf16*)(w + 56 * MB);   // context token-major
  __bf16* VT  = (__bf16*)(w + 72 * MB);   // [bh][64][s'], key-permuted within 32-blocks
  float2* tbl = (float2*)(w + 88 * MB);   // rope table, 512 KB

  // fused cast: x + 4 weights -> bf16 (WQ/WK rows permuted per head)
  cast_all_k<<<3145728 / 256, 256, 0, stream>>>(x, WQ, WK, WV, WO, xb, wqb, wkb, wvb, wob);

  // rope cos/sin table
  rope_tbl_k<<<(SS * 32) / 256, 256, 0, stream>>>(pos, tbl);

  // fused QKV projection + in-lane RoPE(Q,K) + V-transpose (key-permuted)
  gemm_qkv_k<<<dim3(24, MTOT / 128), 256, 0, stream>>>(xb, wqb, wkb, wvb, tbl, Qh, Kh, VT);

  // attention -> context (token-major); 512 perfectly-balanced blocks
  attn10_k<<<dim3(512), 512, 0, stream>>>(Qh, Kh, VT, Cb);

  // output projection (fp32 out)
  gemm_bt_k<float><<<dim3(DM / 128, MTOT / 128), 256, 0, stream>>>(Cb, wob, out, MTOT, DM, DM);
}

// Round 7
// 233.874 us; speedup vs baseline: 1.1140x; 1.0710x over previous
//
#include <hip/hip_runtime.h>
#include <cstdint>
#include <cstddef>

#define DM 1024
#define NH 16
#define DKD 64
#define BB 4
#define SS 2048
#define MTOT (BB*SS)   // 8192 rows

typedef float  f32x4  __attribute__((ext_vector_type(4)));
typedef __bf16 bf16x8 __attribute__((ext_vector_type(8)));
typedef __bf16 bf16x4v __attribute__((ext_vector_type(4)));
typedef __bf16 bf16x2v __attribute__((ext_vector_type(2)));
using as3v = __attribute__((address_space(3))) void;
using as1v = __attribute__((address_space(1))) void;

__device__ __forceinline__ void gl2lds16(const void* g, void* l) {
  __builtin_amdgcn_global_load_lds((as1v*)g, (as3v*)l, 16, 0, 0);
}

__device__ __forceinline__ float fast_exp2(float x) {
#if __has_builtin(__builtin_amdgcn_exp2f)
  return __builtin_amdgcn_exp2f(x);
#else
  return __expf(x * 0.6931471805599453f);
#endif
}

// sin/cos with input in revolutions (v_sin_f32 semantics: D = sin(S*2pi))
__device__ __forceinline__ void sincos_rev(float rev, float* s, float* c) {
#if __has_builtin(__builtin_amdgcn_sinf) && __has_builtin(__builtin_amdgcn_cosf)
  *s = __builtin_amdgcn_sinf(rev);
  *c = __builtin_amdgcn_cosf(rev);
#else
  float a = rev * 6.283185307179586f;
  *s = __sinf(a); *c = __cosf(a);
#endif
}

// pack two f32 -> one u32 of 2 bf16 (compiler emits v_cvt_pk_bf16_f32)
__device__ __forceinline__ uint32_t pkbf(float a, float b) {
  union { uint32_t u; __bf16 h[2]; } c;
  c.h[0] = (__bf16)a; c.h[1] = (__bf16)b;
  return c.u;
}

// ---------------- fused cast fp32 -> bf16 for x + 4 weights ----------------
// WQ/WK rows are permuted per head: even feature d=2i -> i, odd d=2i+1 -> 32+i.
__global__ void cast_all_k(const float* __restrict__ x,
                           const float* __restrict__ wq, const float* __restrict__ wk,
                           const float* __restrict__ wv, const float* __restrict__ wo,
                           __bf16* __restrict__ xb,
                           __bf16* __restrict__ wqb, __bf16* __restrict__ wkb,
                           __bf16* __restrict__ wvb, __bf16* __restrict__ wob) {
  int i = blockIdx.x * blockDim.x + threadIdx.x;   // 3,145,728 float4 groups
  const float* src;
  __bf16* dst;
  int idx, oidx;
  if (i < 2097152) {          // x: 8M elems
    src = x; dst = xb; idx = i; oidx = i;
  } else {
    int j = i - 2097152;
    int w = j >> 18;          // 256K float4 per weight
    idx = j & 262143;
    src = (w == 0) ? wq : (w == 1) ? wk : (w == 2) ? wv : wo;
    dst = (w == 0) ? wqb : (w == 1) ? wkb : (w == 2) ? wvb : wob;
    if (w < 2) {
      int e = idx >> 8;            // output-feature row (1024 floats = 256 f4/row)
      int c = idx & 255;
      int d = e & 63;
      int dp = (d & 1) ? 32 + (d >> 1) : (d >> 1);
      oidx = (((e & ~63) | dp) << 8) | c;
    } else {
      oidx = idx;
    }
  }
  float4 f = ((const float4*)src)[idx];
  bf16x4v o;
  o[0] = (__bf16)f.x; o[1] = (__bf16)f.y; o[2] = (__bf16)f.z; o[3] = (__bf16)f.w;
  ((bf16x4v*)dst)[oidx] = o;
}

// ---------------- RoPE cos/sin table: tbl[s][i] = {cos,sin}(pos[s]*invf_i) --------
__global__ void rope_tbl_k(const int* __restrict__ pos, float2* __restrict__ tbl) {
  int p = blockIdx.x * blockDim.x + threadIdx.x;   // 2048*32
  int s = p >> 5;
  int i = p & 31;
  float ps = (float)pos[s];
  float invr = __expf(-0.28782313663f * (float)i) * 0.15915494309f;  // invf/(2pi)
  float rev = ps * invr;
  rev -= floorf(rev);
  float sn, cs;
  sincos_rev(rev, &sn, &cs);
  tbl[p] = make_float2(cs, sn);
}

// ======== shared GEMM K-loop pieces (v13) ========
// BK=64: half the iterations/barriers of v11/v12, double the per-barrier
// compute (2 K-subtiles of 32 = 32 MFMA/wave/iter). Double-buffered 64 KB
// (2 blocks/CU). Single __syncthreads per iter, stage(next) right after it
// (attn10-proven 2-phase): the NEXT barrier's implicit vmcnt(0) drain finds
// the loads landed after a full (now 2x longer) compute phase.
// LDS layout [row][chunk] with attn-proven XOR swizzle: slot (row, cl) holds
// global chunk cl ^ (row&7) (staged via pre-swizzled per-lane SOURCE address;
// LDS dest stays linear per global_load_lds rule #21). Fragment read chunk
// (tt*4+quad) ^ (row&7) -> 2 lanes/chunk per 16-lane phase group = free.

// ---------------- GEMM: C[M,N] = A[M,K] * B[N,K]^T  (token-major C) ----------------
template <typename CT>
__global__ __launch_bounds__(256, 2) void gemm_bt_k(const __bf16* __restrict__ A,
                                                    const __bf16* __restrict__ B,
                                                    CT* __restrict__ C,
                                                    int M, int N, int K) {
  __shared__ __bf16 As[2][128 * 64];
  __shared__ __bf16 Bs[2][128 * 64];
  const int tid  = threadIdx.x;
  const int lane = tid & 63;
  const int wid  = tid >> 6;
  const int lrow = lane & 15;
  const int quad = lane >> 4;
  const int m0 = blockIdx.y * 128;
  const int n0 = blockIdx.x * 128;
  const int wm = (wid & 1) * 64;
  const int wn = (wid >> 1) * 64;

  // staging: slot s = i*256 + wid*64 + lane; row = s>>3, cl = s&7;
  // source chunk = cl ^ (row&7) = (lane&7) ^ (lane>>3)
  const int lrq  = lane >> 3;                   // 0..7
  const int srow = wid * 8 + lrq;               // row within 32-band
  const int gcol = ((lane & 7) ^ lrq) * 8;      // pre-swizzled source col
  const __bf16* Asrc = A + (size_t)(m0 + srow) * K + gcol;
  const __bf16* Bsrc = B + (size_t)(n0 + srow) * K + gcol;

  f32x4 acc[4][4] = {};

  auto stage = [&](int kt, int bsel) {
    const int k0 = kt * 64;
#pragma unroll
    for (int i = 0; i < 4; ++i)
      gl2lds16(Asrc + (size_t)(i * 32) * K + k0, &As[bsel][(i * 256 + wid * 64) * 8]);
#pragma unroll
    for (int i = 0; i < 4; ++i)
      gl2lds16(Bsrc + (size_t)(i * 32) * K + k0, &Bs[bsel][(i * 256 + wid * 64) * 8]);
  };

  stage(0, 0);
  const int kiters = K >> 6;   // 16
  for (int kk = 0; kk < kiters; ++kk) {
    __syncthreads();                 // drains prev stage (full iter to land) + publish
    if (kk + 1 < kiters) stage(kk + 1, (kk + 1) & 1);
    const __bf16* as = As[kk & 1];
    const __bf16* bs = Bs[kk & 1];
#pragma unroll
    for (int tt = 0; tt < 2; ++tt) {
      bf16x8 af[4], bfr[4];
#pragma unroll
      for (int i = 0; i < 4; ++i)
        af[i] = *(const bf16x8*)(as + (wm + i * 16 + lrow) * 64 + (((tt * 4 + quad) ^ (lrow & 7)) * 8));
#pragma unroll
      for (int i = 0; i < 4; ++i)
        bfr[i] = *(const bf16x8*)(bs + (wn + i * 16 + lrow) * 64 + (((tt * 4 + quad) ^ (lrow & 7)) * 8));
      __builtin_amdgcn_s_setprio(1);
#pragma unroll
      for (int mi = 0; mi < 4; ++mi)
#pragma unroll
        for (int ni = 0; ni < 4; ++ni)
          acc[mi][ni] = __builtin_amdgcn_mfma_f32_16x16x32_bf16(af[mi], bfr[ni], acc[mi][ni], 0, 0, 0);
      __builtin_amdgcn_s_setprio(0);
    }
  }

#pragma unroll
  for (int mi = 0; mi < 4; ++mi)
#pragma unroll
    for (int ni = 0; ni < 4; ++ni)
#pragma unroll
      for (int r = 0; r < 4; ++r) {
        int row = m0 + wm + mi * 16 + quad * 4 + r;
        int col = n0 + wn + ni * 16 + lrow;
        C[(size_t)row * N + col] = (CT)acc[mi][ni][r];
      }
}

// ---------------- fused QKV GEMM + RoPE(Q,K, in-lane) + V-transpose ----------------
// V-store note (v9): VT's key axis is permuted within each 32-token block:
// position 8*quad + 4*(mi&1) + r  <-  original key (mi&1)*16 + quad*4 + r.
// This makes the attention PV A-fragment a direct pack of each lane's own
// QK^T outputs. Softmax is key-order invariant; causal mask untouched.
__global__ __launch_bounds__(256, 2) void gemm_qkv_k(const __bf16* __restrict__ A,
                                                     const __bf16* __restrict__ Bq,
                                                     const __bf16* __restrict__ Bk,
                                                     const __bf16* __restrict__ Bv,
                                                     const float2* __restrict__ tbl,
                                                     __bf16* __restrict__ Cq,
                                                     __bf16* __restrict__ Ck,
                                                     __bf16* __restrict__ Cv) {
  __shared__ __bf16 As[2][128 * 64];
  __shared__ __bf16 Bs[2][128 * 64];
  const int sel = blockIdx.x >> 3;
  const __bf16* B = sel == 0 ? Bq : sel == 1 ? Bk : Bv;
  const int n0 = (blockIdx.x & 7) * 128;
  const int m0 = blockIdx.y * 128;
  const int K = DM;
  const int tid  = threadIdx.x;
  const int lane = tid & 63;
  const int wid  = tid >> 6;
  const int lrow = lane & 15;
  const int quad = lane >> 4;
  const int wm = (wid & 1) * 64;
  const int wn = (wid >> 1) * 64;

  const int lrq  = lane >> 3;
  const int srow = wid * 8 + lrq;
  const int gcol = ((lane & 7) ^ lrq) * 8;
  const __bf16* Asrc = A + (size_t)(m0 + srow) * K + gcol;
  const __bf16* Bsrc = B + (size_t)(n0 + srow) * K + gcol;

  f32x4 acc[4][4] = {};

  auto stage = [&](int kt, int bsel) {
    const int k0 = kt * 64;
#pragma unroll
    for (int i = 0; i < 4; ++i)
      gl2lds16(Asrc + (size_t)(i * 32) * K + k0, &As[bsel][(i * 256 + wid * 64) * 8]);
#pragma unroll
    for (int i = 0; i < 4; ++i)
      gl2lds16(Bsrc + (size_t)(i * 32) * K + k0, &Bs[bsel][(i * 256 + wid * 64) * 8]);
  };

  stage(0, 0);
  const int kiters = K >> 6;   // 16
  for (int kk = 0; kk < kiters; ++kk) {
    __syncthreads();
    if (kk + 1 < kiters) stage(kk + 1, (kk + 1) & 1);
    const __bf16* as = As[kk & 1];
    const __bf16* bs = Bs[kk & 1];
#pragma unroll
    for (int tt = 0; tt < 2; ++tt) {
      bf16x8 af[4], bfr[4];
#pragma unroll
      for (int i = 0; i < 4; ++i)
        af[i] = *(const bf16x8*)(as + (wm + i * 16 + lrow) * 64 + (((tt * 4 + quad) ^ (lrow & 7)) * 8));
#pragma unroll
      for (int i = 0; i < 4; ++i)
        bfr[i] = *(const bf16x8*)(bs + (wn + i * 16 + lrow) * 64 + (((tt * 4 + quad) ^ (lrow & 7)) * 8));
      __builtin_amdgcn_s_setprio(1);
#pragma unroll
      for (int mi = 0; mi < 4; ++mi)
#pragma unroll
        for (int ni = 0; ni < 4; ++ni)
          acc[mi][ni] = __builtin_amdgcn_mfma_f32_16x16x32_bf16(af[mi], bfr[ni], acc[mi][ni], 0, 0, 0);
      __builtin_amdgcn_s_setprio(0);
    }
  }

  const int hbase = (n0 + wn) >> 6;   // head index for this wave's 64-col block
  const int bq = m0 >> 11;            // batch (128-row tile never crosses batch)

  if (sel == 2) {
    // V: store transposed into VT [bh][64][s'], s' = within-32-block permuted key
    __bf16* vt = Cv + ((size_t)(bq * NH + hbase)) * (DKD * SS);
    const int S0 = (m0 + wm) & (SS - 1);          // multiple of 64
#pragma unroll
    for (int ni = 0; ni < 4; ++ni) {
      const int d = ni * 16 + lrow;
#pragma unroll
      for (int mi = 0; mi < 4; ++mi) {
        bf16x4v pk;
#pragma unroll
        for (int r = 0; r < 4; ++r) pk[r] = (__bf16)acc[mi][ni][r];
        const int sp = S0 + (mi >> 1) * 32 + quad * 8 + (mi & 1) * 4;  // permuted pos
        *(bf16x4v*)(vt + (size_t)d * SS + sp) = pk;
      }
    }
  } else {
    // Q or K: in-lane RoPE via table. Pair = (acc[.][ni], acc[.][ni+2]), i = ni*16+lrow.
    __bf16* C = ((sel == 0) ? Cq : Ck) + ((size_t)(bq * NH + hbase)) * (SS * DKD);
#pragma unroll
    for (int ni = 0; ni < 2; ++ni) {
      const int i = ni * 16 + lrow;                 // pair index 0..31
#pragma unroll
      for (int mi = 0; mi < 4; ++mi) {
#pragma unroll
        for (int r = 0; r < 4; ++r) {
          int s = (m0 + wm + mi * 16 + quad * 4 + r) & (SS - 1);
          float2 cssn = tbl[s * 32 + i];
          float a = acc[mi][ni][r];       // x1 (even feature of the pair)
          float b = acc[mi][ni + 2][r];   // x2 (odd feature)
          C[(size_t)s * DKD + i]      = (__bf16)fmaf(a, cssn.x, -(b * cssn.y)); // x1 c - x2 s
          C[(size_t)s * DKD + 32 + i] = (__bf16)fmaf(a, cssn.y,  (b * cssn.x)); // x1 s + x2 c
        }
      }
    }
  }
}

// ---------------- attention v10: paired q-tiles, perfectly balanced blocks ----------
//  One block = q-tile pair (pr, 15-pr) -> every block runs EXACTLY 17 key-tile
//  iterations; 512 blocks = 2/CU, single round, zero tail. Double-buffer
//  pipeline carries across the segment boundary.
__global__ __launch_bounds__(512, 4) void attn10_k(const __bf16* __restrict__ Qh,
                                                   const __bf16* __restrict__ Kh,
                                                   const __bf16* __restrict__ VT,
                                                   __bf16* __restrict__ O) {
  __shared__ __bf16 Ks[2][128 * 64];   // swizzled [key][chunk8], double-buffered
  __shared__ __bf16 Vt[2][64 * 128];   // swizzled [dk][chunk8 of 16], double-buffered
  const int tid  = threadIdx.x;
  const int lane = tid & 63;
  const int wid  = tid >> 6;           // 0..7
  const int lrow = lane & 15;
  const int quad = lane >> 4;
  const int j   = blockIdx.x;          // 0..511
  const int xcd = j & 7;
  const int t   = j >> 3;              // 0..63
  const int bh  = (xcd << 3) | (t >> 3);
  const int pr  = t & 7;
  const int qa  = pr;                  // segment-0 q-tile (qa+1 key-tiles)
  const int qb  = 15 - pr;             // segment-1 q-tile (16-pr key-tiles); total 17
  const int na  = qa + 1;
  const int b  = bh >> 4;
  const int h  = bh & 15;
  const size_t hb = (size_t)bh * (SS * DKD);

  const int skr = lane >> 3;   // K staging: row-local 0..7
  const int skc = lane & 7;    //            chunk 0..7
  const int svd = lane >> 4;   // V staging: dk-local 0..3
  const int svc = lane & 15;   //            chunk 0..15

  auto stage = [&](int kt, int bsel) {
#pragma unroll
    for (int ii = 0; ii < 2; ++ii) {
      int i = wid * 2 + ii;          // 0..15
      int key = i * 8 + skr;
      int gc = skc ^ (key & 7);
      gl2lds16(Kh + hb + (size_t)(kt * 128 + key) * DKD + gc * 8, &Ks[bsel][i * 512]);
      int dk = i * 4 + svd;
      int gc2 = (svc & 8) | ((svc ^ dk) & 7);
      gl2lds16(VT + hb + (size_t)dk * SS + kt * 128 + gc2 * 8, &Vt[bsel][i * 512]);
    }
  };

  // prologue: key-tile 0 (segment 0) in flight
  stage(0, 0);
  int it = 0;   // global iteration index 0..16; LDS buffer parity = it & 1

  for (int seg = 0; seg < 2; ++seg) {
    const int qi  = seg ? qb : qa;
    const int q0  = qi * 128;
    const int nkt = qi + 1;
    const int qg  = q0 + wid * 16 + lrow;  // this lane's q-row (col of S^T)

    bf16x8 qf0, qf1;
    {
      const __bf16* qp = Qh + hb + (size_t)qg * DKD + quad * 8;
      qf0 = *(const bf16x8*)qp;
      qf1 = *(const bf16x8*)(qp + 32);
    }
    f32x4 Oa[4] = {};
    float la = 0.f, lb = 0.f;   // split l-chain (serial fp adds not reassociable)

    for (int kt = 0; kt < nkt; ++kt, ++it) {
      __syncthreads();
      {
        int nit = it + 1;
        if (nit < 17) {
          int nk = (nit < na) ? nit : (nit - na);   // next key-tile (crosses segs)
          stage(nk, nit & 1);
        }
      }
      const __bf16* ks = Ks[it & 1];
      const __bf16* vt = Vt[it & 1];

      // S^T = K * Q^T : A = K-frag (m=key), B = Q-frag (n=q)
      f32x4 sa[8];
#pragma unroll
      for (int mi = 0; mi < 8; ++mi) sa[mi] = (f32x4){0.f, 0.f, 0.f, 0.f};
      __builtin_amdgcn_s_setprio(1);
#pragma unroll
      for (int tt = 0; tt < 2; ++tt) {
        bf16x8 qf = tt ? qf1 : qf0;
#pragma unroll
        for (int mi = 0; mi < 8; ++mi) {
          bf16x8 kf = *(const bf16x8*)(ks + (mi * 16 + lrow) * 64 + (((tt * 4 + quad) ^ (lrow & 7)) * 8));
          sa[mi] = __builtin_amdgcn_mfma_f32_16x16x32_bf16(kf, qf, sa[mi], 0, 0, 0);
        }
      }
      __builtin_amdgcn_s_setprio(0);

      // fused softmax + direct pack + PV, per 32-key block kc.
      const bool lastt = (kt == nkt - 1);
#pragma unroll
      for (int kc = 0; kc < 4; ++kc) {
        union { uint32_t u[4]; bf16x8 v; } P;
#pragma unroll
        for (int half = 0; half < 2; ++half) {
          const int mi = kc * 2 + half;
          float pr4[4];
#pragma unroll
          for (int r = 0; r < 4; ++r) {
            float p = fast_exp2(sa[mi][r] * 0.18033688f - 8.0f);
            if (lastt) {
              int key = kt * 128 + kc * 32 + half * 16 + quad * 4 + r;
              p = (key <= qg) ? p : 0.f;
            }
            pr4[r] = p;
          }
          float s01 = pr4[0] + pr4[1];
          float s23 = pr4[2] + pr4[3];
          if (half) lb += (s01 + s23); else la += (s01 + s23);
          P.u[half * 2]     = pkbf(pr4[0], pr4[1]);
          P.u[half * 2 + 1] = pkbf(pr4[2], pr4[3]);
        }
        __builtin_amdgcn_s_setprio(1);
#pragma unroll
        for (int ni = 0; ni < 4; ++ni) {
          int c = kc * 4 + quad;
          int cp = (c & 8) | ((c ^ (lrow & 7)) & 7);
          bf16x8 vf = *(const bf16x8*)(vt + (ni * 16 + lrow) * 128 + cp * 8);
          Oa[ni] = __builtin_amdgcn_mfma_f32_16x16x32_bf16(P.v, vf, Oa[ni], 0, 0, 0);
        }
        __builtin_amdgcn_s_setprio(0);
      }
    }

    // per-segment epilogue: l reduction across quads, normalize, store
    float l = la + lb;
    l += __shfl_xor(l, 16, 64);
    l += __shfl_xor(l, 32, 64);
#pragma unroll
    for (int r = 0; r < 4; ++r) {
      float li = __shfl(l, quad * 4 + r, 64);   // l for q-row quad*4+r
      float inv = 1.0f / li;
      int row = q0 + wid * 16 + quad * 4 + r;
#pragma unroll
      for (int ni = 0; ni < 4; ++ni)
        O[(size_t)b * SS * DM + (size_t)row * DM + h * DKD + ni * 16 + lrow] =
            (__bf16)(Oa[ni][r] * inv);
    }
  }
}

// ---------------- launch ----------------
extern "C" void kernel_launch(void* const* d_in, const int* in_sizes, int n_in,
                              void* d_out, int out_size, void* d_ws, size_t ws_size,
                              hipStream_t stream) {
  (void)in_sizes; (void)n_in; (void)out_size; (void)ws_size;
  const float* x  = (const float*)d_in[0];
  const int*   pos = (const int*)d_in[1];
  const float* WQ = (const float*)d_in[2];
  const float* WK = (const float*)d_in[3];
  const float* WV = (const float*)d_in[4];
  const float* WO = (const float*)d_in[5];
  float* out = (float*)d_out;

  char* w = (char*)d_ws;
  const size_t MB = 1024 * 1024;
  __bf16* xb  = (__bf16*)(w);             // 16 MB
  __bf16* wqb = (__bf16*)(w + 16 * MB);   // permuted rows
  __bf16* wkb = (__bf16*)(w + 18 * MB);   // permuted rows
  __bf16* wvb = (__bf16*)(w + 20 * MB);
  __bf16* wob = (__bf16*)(w + 22 * MB);
  __bf16* Qh  = (__bf16*)(w + 24 * MB);   // head-major [bh][s][64], RoPE'd (permuted d)
  __bf16* Kh  = (__bf16*)(w + 40 * MB);   // head-major [bh][s][64], RoPE'd (permuted d)
  __bf16* Cb  = (__bf16*)(w + 56 * MB);   // context token-major
  __bf16* VT  = (__bf16*)(w + 72 * MB);   // [bh][64][s'], key-permuted within 32-blocks
  float2* tbl = (float2*)(w + 88 * MB);   // rope table, 512 KB

  // fused cast: x + 4 weights -> bf16 (WQ/WK rows permuted per head)
  cast_all_k<<<3145728 / 256, 256, 0, stream>>>(x, WQ, WK, WV, WO, xb, wqb, wkb, wvb, wob);

  // rope cos/sin table
  rope_tbl_k<<<(SS * 32) / 256, 256, 0, stream>>>(pos, tbl);

  // fused QKV projection + in-lane RoPE(Q,K) + V-transpose (key-permuted)
  gemm_qkv_k<<<dim3(24, MTOT / 128), 256, 0, stream>>>(xb, wqb, wkb, wvb, tbl, Qh, Kh, VT);

  // attention -> context (token-major); 512 perfectly-balanced blocks
  attn10_k<<<dim3(512), 512, 0, stream>>>(Qh, Kh, VT, Cb);

  // output projection (fp32 out)
  gemm_bt_k<float><<<dim3(DM / 128, MTOT / 128), 256, 0, stream>>>(Cb, wob, out, MTOT, DM, DM);
}

// Round 8
// 233.716 us; speedup vs baseline: 1.1148x; 1.0007x over previous
//
#include <hip/hip_runtime.h>
#include <cstdint>
#include <cstddef>

#define DM 1024
#define NH 16
#define DKD 64
#define BB 4
#define SS 2048
#define MTOT (BB*SS)   // 8192 rows

typedef float  f32x4  __attribute__((ext_vector_type(4)));
typedef __bf16 bf16x8 __attribute__((ext_vector_type(8)));
typedef __bf16 bf16x4v __attribute__((ext_vector_type(4)));
typedef __bf16 bf16x2v __attribute__((ext_vector_type(2)));
using as3v = __attribute__((address_space(3))) void;
using as1v = __attribute__((address_space(1))) void;

__device__ __forceinline__ void gl2lds16(const void* g, void* l) {
  __builtin_amdgcn_global_load_lds((as1v*)g, (as3v*)l, 16, 0, 0);
}

__device__ __forceinline__ float fast_exp2(float x) {
#if __has_builtin(__builtin_amdgcn_exp2f)
  return __builtin_amdgcn_exp2f(x);
#else
  return __expf(x * 0.6931471805599453f);
#endif
}

// sin/cos with input in revolutions (v_sin_f32 semantics: D = sin(S*2pi))
__device__ __forceinline__ void sincos_rev(float rev, float* s, float* c) {
#if __has_builtin(__builtin_amdgcn_sinf) && __has_builtin(__builtin_amdgcn_cosf)
  *s = __builtin_amdgcn_sinf(rev);
  *c = __builtin_amdgcn_cosf(rev);
#else
  float a = rev * 6.283185307179586f;
  *s = __sinf(a); *c = __cosf(a);
#endif
}

// pack two f32 -> one u32 of 2 bf16 (compiler emits v_cvt_pk_bf16_f32)
__device__ __forceinline__ uint32_t pkbf(float a, float b) {
  union { uint32_t u; __bf16 h[2]; } c;
  c.h[0] = (__bf16)a; c.h[1] = (__bf16)b;
  return c.u;
}

// ---------------- fused cast fp32 -> bf16 for x + 4 weights ----------------
// WQ/WK rows are permuted per head: even feature d=2i -> i, odd d=2i+1 -> 32+i.
__global__ void cast_all_k(const float* __restrict__ x,
                           const float* __restrict__ wq, const float* __restrict__ wk,
                           const float* __restrict__ wv, const float* __restrict__ wo,
                           __bf16* __restrict__ xb,
                           __bf16* __restrict__ wqb, __bf16* __restrict__ wkb,
                           __bf16* __restrict__ wvb, __bf16* __restrict__ wob) {
  int i = blockIdx.x * blockDim.x + threadIdx.x;   // 3,145,728 float4 groups
  const float* src;
  __bf16* dst;
  int idx, oidx;
  if (i < 2097152) {          // x: 8M elems
    src = x; dst = xb; idx = i; oidx = i;
  } else {
    int j = i - 2097152;
    int w = j >> 18;          // 256K float4 per weight
    idx = j & 262143;
    src = (w == 0) ? wq : (w == 1) ? wk : (w == 2) ? wv : wo;
    dst = (w == 0) ? wqb : (w == 1) ? wkb : (w == 2) ? wvb : wob;
    if (w < 2) {
      int e = idx >> 8;            // output-feature row (1024 floats = 256 f4/row)
      int c = idx & 255;
      int d = e & 63;
      int dp = (d & 1) ? 32 + (d >> 1) : (d >> 1);
      oidx = (((e & ~63) | dp) << 8) | c;
    } else {
      oidx = idx;
    }
  }
  float4 f = ((const float4*)src)[idx];
  bf16x4v o;
  o[0] = (__bf16)f.x; o[1] = (__bf16)f.y; o[2] = (__bf16)f.z; o[3] = (__bf16)f.w;
  ((bf16x4v*)dst)[oidx] = o;
}

// ---------------- RoPE cos/sin table: tbl[s][i] = {cos,sin}(pos[s]*invf_i) --------
__global__ void rope_tbl_k(const int* __restrict__ pos, float2* __restrict__ tbl) {
  int p = blockIdx.x * blockDim.x + threadIdx.x;   // 2048*32
  int s = p >> 5;
  int i = p & 31;
  float ps = (float)pos[s];
  float invr = __expf(-0.28782313663f * (float)i) * 0.15915494309f;  // invf/(2pi)
  float rev = ps * invr;
  rev -= floorf(rev);
  float sn, cs;
  sincos_rev(rev, &sn, &cs);
  tbl[p] = make_float2(cs, sn);
}

// ======== shared GEMM K-loop pieces (v14) ========
// v13 core (BK=64, 2-phase single-barrier, XOR content swizzle, conflicts=0)
// + T1 XCD-chunked tile assignment: bid&7 = XCD (HW round-robin), each XCD
// owns m-tiles [xcd*8 .. xcd*8+7] (A slice 2MB resident in its 4MB L2) and
// sweeps columns with m fastest -> B-tile hot for 8 consecutive blocks.
// v13 grid had the 24 same-A blocks round-robined over 8 XCDs -> 8x A
// re-fetch (FETCH 83MB vs 22MB ideal). Pure index permutation; no schedule
// change.

// ---------------- GEMM: C[M,N] = A[M,K] * B[N,K]^T  (token-major C) ----------------
// grid: 1D, (M/128/8 per-XCD m-tiles) x (N/128 cols) x 8 XCDs; m fastest.
template <typename CT>
__global__ __launch_bounds__(256, 2) void gemm_bt_k(const __bf16* __restrict__ A,
                                                    const __bf16* __restrict__ B,
                                                    CT* __restrict__ C,
                                                    int M, int N, int K) {
  __shared__ __bf16 As[2][128 * 64];
  __shared__ __bf16 Bs[2][128 * 64];
  const int tid  = threadIdx.x;
  const int lane = tid & 63;
  const int wid  = tid >> 6;
  const int lrow = lane & 15;
  const int quad = lane >> 4;
  const int bid  = blockIdx.x;
  const int xcd  = bid & 7;
  const int t    = bid >> 3;
  const int mpx  = (M >> 7) >> 3;          // m-tiles per XCD (8 for M=8192)
  const int col  = t / mpx;
  const int mloc = t - col * mpx;
  const int m0 = (xcd * mpx + mloc) * 128;
  const int n0 = col * 128;
  const int wm = (wid & 1) * 64;
  const int wn = (wid >> 1) * 64;

  // staging: slot s = i*256 + wid*64 + lane; row = s>>3, cl = s&7;
  // source chunk = cl ^ (row&7) = (lane&7) ^ (lane>>3)
  const int lrq  = lane >> 3;                   // 0..7
  const int srow = wid * 8 + lrq;               // row within 32-band
  const int gcol = ((lane & 7) ^ lrq) * 8;      // pre-swizzled source col
  const __bf16* Asrc = A + (size_t)(m0 + srow) * K + gcol;
  const __bf16* Bsrc = B + (size_t)(n0 + srow) * K + gcol;

  f32x4 acc[4][4] = {};

  auto stage = [&](int kt, int bsel) {
    const int k0 = kt * 64;
#pragma unroll
    for (int i = 0; i < 4; ++i)
      gl2lds16(Asrc + (size_t)(i * 32) * K + k0, &As[bsel][(i * 256 + wid * 64) * 8]);
#pragma unroll
    for (int i = 0; i < 4; ++i)
      gl2lds16(Bsrc + (size_t)(i * 32) * K + k0, &Bs[bsel][(i * 256 + wid * 64) * 8]);
  };

  stage(0, 0);
  const int kiters = K >> 6;   // 16
  for (int kk = 0; kk < kiters; ++kk) {
    __syncthreads();                 // drains prev stage (full iter to land) + publish
    if (kk + 1 < kiters) stage(kk + 1, (kk + 1) & 1);
    const __bf16* as = As[kk & 1];
    const __bf16* bs = Bs[kk & 1];
#pragma unroll
    for (int tt = 0; tt < 2; ++tt) {
      bf16x8 af[4], bfr[4];
#pragma unroll
      for (int i = 0; i < 4; ++i)
        af[i] = *(const bf16x8*)(as + (wm + i * 16 + lrow) * 64 + (((tt * 4 + quad) ^ (lrow & 7)) * 8));
#pragma unroll
      for (int i = 0; i < 4; ++i)
        bfr[i] = *(const bf16x8*)(bs + (wn + i * 16 + lrow) * 64 + (((tt * 4 + quad) ^ (lrow & 7)) * 8));
      __builtin_amdgcn_s_setprio(1);
#pragma unroll
      for (int mi = 0; mi < 4; ++mi)
#pragma unroll
        for (int ni = 0; ni < 4; ++ni)
          acc[mi][ni] = __builtin_amdgcn_mfma_f32_16x16x32_bf16(af[mi], bfr[ni], acc[mi][ni], 0, 0, 0);
      __builtin_amdgcn_s_setprio(0);
    }
  }

#pragma unroll
  for (int mi = 0; mi < 4; ++mi)
#pragma unroll
    for (int ni = 0; ni < 4; ++ni)
#pragma unroll
      for (int r = 0; r < 4; ++r) {
        int row = m0 + wm + mi * 16 + quad * 4 + r;
        int col2 = n0 + wn + ni * 16 + lrow;
        C[(size_t)row * N + col2] = (CT)acc[mi][ni][r];
      }
}

// ---------------- fused QKV GEMM + RoPE(Q,K, in-lane) + V-transpose ----------------
// V-store note (v9): VT's key axis is permuted within each 32-token block:
// position 8*quad + 4*(mi&1) + r  <-  original key (mi&1)*16 + quad*4 + r.
// This makes the attention PV A-fragment a direct pack of each lane's own
// QK^T outputs. Softmax is key-order invariant; causal mask untouched.
// grid: 1D 1536 = 8 XCD x (8 m-tiles x 24 cols), m fastest within col.
__global__ __launch_bounds__(256, 2) void gemm_qkv_k(const __bf16* __restrict__ A,
                                                     const __bf16* __restrict__ Bq,
                                                     const __bf16* __restrict__ Bk,
                                                     const __bf16* __restrict__ Bv,
                                                     const float2* __restrict__ tbl,
                                                     __bf16* __restrict__ Cq,
                                                     __bf16* __restrict__ Ck,
                                                     __bf16* __restrict__ Cv) {
  __shared__ __bf16 As[2][128 * 64];
  __shared__ __bf16 Bs[2][128 * 64];
  const int bid  = blockIdx.x;
  const int xcd  = bid & 7;
  const int t    = bid >> 3;           // 0..191
  const int col  = t >> 3;             // 0..23  (sel*8 + n-tile)
  const int mloc = t & 7;
  const int sel  = col >> 3;
  const __bf16* B = sel == 0 ? Bq : sel == 1 ? Bk : Bv;
  const int n0 = (col & 7) * 128;
  const int m0 = (xcd * 8 + mloc) * 128;
  const int K = DM;
  const int tid  = threadIdx.x;
  const int lane = tid & 63;
  const int wid  = tid >> 6;
  const int lrow = lane & 15;
  const int quad = lane >> 4;
  const int wm = (wid & 1) * 64;
  const int wn = (wid >> 1) * 64;

  const int lrq  = lane >> 3;
  const int srow = wid * 8 + lrq;
  const int gcol = ((lane & 7) ^ lrq) * 8;
  const __bf16* Asrc = A + (size_t)(m0 + srow) * K + gcol;
  const __bf16* Bsrc = B + (size_t)(n0 + srow) * K + gcol;

  f32x4 acc[4][4] = {};

  auto stage = [&](int kt, int bsel) {
    const int k0 = kt * 64;
#pragma unroll
    for (int i = 0; i < 4; ++i)
      gl2lds16(Asrc + (size_t)(i * 32) * K + k0, &As[bsel][(i * 256 + wid * 64) * 8]);
#pragma unroll
    for (int i = 0; i < 4; ++i)
      gl2lds16(Bsrc + (size_t)(i * 32) * K + k0, &Bs[bsel][(i * 256 + wid * 64) * 8]);
  };

  stage(0, 0);
  const int kiters = K >> 6;   // 16
  for (int kk = 0; kk < kiters; ++kk) {
    __syncthreads();
    if (kk + 1 < kiters) stage(kk + 1, (kk + 1) & 1);
    const __bf16* as = As[kk & 1];
    const __bf16* bs = Bs[kk & 1];
#pragma unroll
    for (int tt = 0; tt < 2; ++tt) {
      bf16x8 af[4], bfr[4];
#pragma unroll
      for (int i = 0; i < 4; ++i)
        af[i] = *(const bf16x8*)(as + (wm + i * 16 + lrow) * 64 + (((tt * 4 + quad) ^ (lrow & 7)) * 8));
#pragma unroll
      for (int i = 0; i < 4; ++i)
        bfr[i] = *(const bf16x8*)(bs + (wn + i * 16 + lrow) * 64 + (((tt * 4 + quad) ^ (lrow & 7)) * 8));
      __builtin_amdgcn_s_setprio(1);
#pragma unroll
      for (int mi = 0; mi < 4; ++mi)
#pragma unroll
        for (int ni = 0; ni < 4; ++ni)
          acc[mi][ni] = __builtin_amdgcn_mfma_f32_16x16x32_bf16(af[mi], bfr[ni], acc[mi][ni], 0, 0, 0);
      __builtin_amdgcn_s_setprio(0);
    }
  }

  const int hbase = (n0 + wn) >> 6;   // head index for this wave's 64-col block
  const int bq = m0 >> 11;            // batch (128-row tile never crosses batch)

  if (sel == 2) {
    // V: store transposed into VT [bh][64][s'], s' = within-32-block permuted key
    __bf16* vt = Cv + ((size_t)(bq * NH + hbase)) * (DKD * SS);
    const int S0 = (m0 + wm) & (SS - 1);          // multiple of 64
#pragma unroll
    for (int ni = 0; ni < 4; ++ni) {
      const int d = ni * 16 + lrow;
#pragma unroll
      for (int mi = 0; mi < 4; ++mi) {
        bf16x4v pk;
#pragma unroll
        for (int r = 0; r < 4; ++r) pk[r] = (__bf16)acc[mi][ni][r];
        const int sp = S0 + (mi >> 1) * 32 + quad * 8 + (mi & 1) * 4;  // permuted pos
        *(bf16x4v*)(vt + (size_t)d * SS + sp) = pk;
      }
    }
  } else {
    // Q or K: in-lane RoPE via table. Pair = (acc[.][ni], acc[.][ni+2]), i = ni*16+lrow.
    __bf16* C = ((sel == 0) ? Cq : Ck) + ((size_t)(bq * NH + hbase)) * (SS * DKD);
#pragma unroll
    for (int ni = 0; ni < 2; ++ni) {
      const int i = ni * 16 + lrow;                 // pair index 0..31
#pragma unroll
      for (int mi = 0; mi < 4; ++mi) {
#pragma unroll
        for (int r = 0; r < 4; ++r) {
          int s = (m0 + wm + mi * 16 + quad * 4 + r) & (SS - 1);
          float2 cssn = tbl[s * 32 + i];
          float a = acc[mi][ni][r];       // x1 (even feature of the pair)
          float b = acc[mi][ni + 2][r];   // x2 (odd feature)
          C[(size_t)s * DKD + i]      = (__bf16)fmaf(a, cssn.x, -(b * cssn.y)); // x1 c - x2 s
          C[(size_t)s * DKD + 32 + i] = (__bf16)fmaf(a, cssn.y,  (b * cssn.x)); // x1 s + x2 c
        }
      }
    }
  }
}

// ---------------- attention v10: paired q-tiles, perfectly balanced blocks ----------
//  One block = q-tile pair (pr, 15-pr) -> every block runs EXACTLY 17 key-tile
//  iterations; 512 blocks = 2/CU, single round, zero tail. Double-buffer
//  pipeline carries across the segment boundary.
__global__ __launch_bounds__(512, 4) void attn10_k(const __bf16* __restrict__ Qh,
                                                   const __bf16* __restrict__ Kh,
                                                   const __bf16* __restrict__ VT,
                                                   __bf16* __restrict__ O) {
  __shared__ __bf16 Ks[2][128 * 64];   // swizzled [key][chunk8], double-buffered
  __shared__ __bf16 Vt[2][64 * 128];   // swizzled [dk][chunk8 of 16], double-buffered
  const int tid  = threadIdx.x;
  const int lane = tid & 63;
  const int wid  = tid >> 6;           // 0..7
  const int lrow = lane & 15;
  const int quad = lane >> 4;
  const int j   = blockIdx.x;          // 0..511
  const int xcd = j & 7;
  const int t   = j >> 3;              // 0..63
  const int bh  = (xcd << 3) | (t >> 3);
  const int pr  = t & 7;
  const int qa  = pr;                  // segment-0 q-tile (qa+1 key-tiles)
  const int qb  = 15 - pr;             // segment-1 q-tile (16-pr key-tiles); total 17
  const int na  = qa + 1;
  const int b  = bh >> 4;
  const int h  = bh & 15;
  const size_t hb = (size_t)bh * (SS * DKD);

  const int skr = lane >> 3;   // K staging: row-local 0..7
  const int skc = lane & 7;    //            chunk 0..7
  const int svd = lane >> 4;   // V staging: dk-local 0..3
  const int svc = lane & 15;   //            chunk 0..15

  auto stage = [&](int kt, int bsel) {
#pragma unroll
    for (int ii = 0; ii < 2; ++ii) {
      int i = wid * 2 + ii;          // 0..15
      int key = i * 8 + skr;
      int gc = skc ^ (key & 7);
      gl2lds16(Kh + hb + (size_t)(kt * 128 + key) * DKD + gc * 8, &Ks[bsel][i * 512]);
      int dk = i * 4 + svd;
      int gc2 = (svc & 8) | ((svc ^ dk) & 7);
      gl2lds16(VT + hb + (size_t)dk * SS + kt * 128 + gc2 * 8, &Vt[bsel][i * 512]);
    }
  };

  // prologue: key-tile 0 (segment 0) in flight
  stage(0, 0);
  int it = 0;   // global iteration index 0..16; LDS buffer parity = it & 1

  for (int seg = 0; seg < 2; ++seg) {
    const int qi  = seg ? qb : qa;
    const int q0  = qi * 128;
    const int nkt = qi + 1;
    const int qg  = q0 + wid * 16 + lrow;  // this lane's q-row (col of S^T)

    bf16x8 qf0, qf1;
    {
      const __bf16* qp = Qh + hb + (size_t)qg * DKD + quad * 8;
      qf0 = *(const bf16x8*)qp;
      qf1 = *(const bf16x8*)(qp + 32);
    }
    f32x4 Oa[4] = {};
    float la = 0.f, lb = 0.f;   // split l-chain (serial fp adds not reassociable)

    for (int kt = 0; kt < nkt; ++kt, ++it) {
      __syncthreads();
      {
        int nit = it + 1;
        if (nit < 17) {
          int nk = (nit < na) ? nit : (nit - na);   // next key-tile (crosses segs)
          stage(nk, nit & 1);
        }
      }
      const __bf16* ks = Ks[it & 1];
      const __bf16* vt = Vt[it & 1];

      // S^T = K * Q^T : A = K-frag (m=key), B = Q-frag (n=q)
      f32x4 sa[8];
#pragma unroll
      for (int mi = 0; mi < 8; ++mi) sa[mi] = (f32x4){0.f, 0.f, 0.f, 0.f};
      __builtin_amdgcn_s_setprio(1);
#pragma unroll
      for (int tt = 0; tt < 2; ++tt) {
        bf16x8 qf = tt ? qf1 : qf0;
#pragma unroll
        for (int mi = 0; mi < 8; ++mi) {
          bf16x8 kf = *(const bf16x8*)(ks + (mi * 16 + lrow) * 64 + (((tt * 4 + quad) ^ (lrow & 7)) * 8));
          sa[mi] = __builtin_amdgcn_mfma_f32_16x16x32_bf16(kf, qf, sa[mi], 0, 0, 0);
        }
      }
      __builtin_amdgcn_s_setprio(0);

      // fused softmax + direct pack + PV, per 32-key block kc.
      const bool lastt = (kt == nkt - 1);
#pragma unroll
      for (int kc = 0; kc < 4; ++kc) {
        union { uint32_t u[4]; bf16x8 v; } P;
#pragma unroll
        for (int half = 0; half < 2; ++half) {
          const int mi = kc * 2 + half;
          float pr4[4];
#pragma unroll
          for (int r = 0; r < 4; ++r) {
            float p = fast_exp2(sa[mi][r] * 0.18033688f - 8.0f);
            if (lastt) {
              int key = kt * 128 + kc * 32 + half * 16 + quad * 4 + r;
              p = (key <= qg) ? p : 0.f;
            }
            pr4[r] = p;
          }
          float s01 = pr4[0] + pr4[1];
          float s23 = pr4[2] + pr4[3];
          if (half) lb += (s01 + s23); else la += (s01 + s23);
          P.u[half * 2]     = pkbf(pr4[0], pr4[1]);
          P.u[half * 2 + 1] = pkbf(pr4[2], pr4[3]);
        }
        __builtin_amdgcn_s_setprio(1);
#pragma unroll
        for (int ni = 0; ni < 4; ++ni) {
          int c = kc * 4 + quad;
          int cp = (c & 8) | ((c ^ (lrow & 7)) & 7);
          bf16x8 vf = *(const bf16x8*)(vt + (ni * 16 + lrow) * 128 + cp * 8);
          Oa[ni] = __builtin_amdgcn_mfma_f32_16x16x32_bf16(P.v, vf, Oa[ni], 0, 0, 0);
        }
        __builtin_amdgcn_s_setprio(0);
      }
    }

    // per-segment epilogue: l reduction across quads, normalize, store
    float l = la + lb;
    l += __shfl_xor(l, 16, 64);
    l += __shfl_xor(l, 32, 64);
#pragma unroll
    for (int r = 0; r < 4; ++r) {
      float li = __shfl(l, quad * 4 + r, 64);   // l for q-row quad*4+r
      float inv = 1.0f / li;
      int row = q0 + wid * 16 + quad * 4 + r;
#pragma unroll
      for (int ni = 0; ni < 4; ++ni)
        O[(size_t)b * SS * DM + (size_t)row * DM + h * DKD + ni * 16 + lrow] =
            (__bf16)(Oa[ni][r] * inv);
    }
  }
}

// ---------------- launch ----------------
extern "C" void kernel_launch(void* const* d_in, const int* in_sizes, int n_in,
                              void* d_out, int out_size, void* d_ws, size_t ws_size,
                              hipStream_t stream) {
  (void)in_sizes; (void)n_in; (void)out_size; (void)ws_size;
  const float* x  = (const float*)d_in[0];
  const int*   pos = (const int*)d_in[1];
  const float* WQ = (const float*)d_in[2];
  const float* WK = (const float*)d_in[3];
  const float* WV = (const float*)d_in[4];
  const float* WO = (const float*)d_in[5];
  float* out = (float*)d_out;

  char* w = (char*)d_ws;
  const size_t MB = 1024 * 1024;
  __bf16* xb  = (__bf16*)(w);             // 16 MB
  __bf16* wqb = (__bf16*)(w + 16 * MB);   // permuted rows
  __bf16* wkb = (__bf16*)(w + 18 * MB);   // permuted rows
  __bf16* wvb = (__bf16*)(w + 20 * MB);
  __bf16* wob = (__bf16*)(w + 22 * MB);
  __bf16* Qh  = (__bf16*)(w + 24 * MB);   // head-major [bh][s][64], RoPE'd (permuted d)
  __bf16* Kh  = (__bf16*)(w + 40 * MB);   // head-major [bh][s][64], RoPE'd (permuted d)
  __bf16* Cb  = (__bf16*)(w + 56 * MB);   // context token-major
  __bf16* VT  = (__bf16*)(w + 72 * MB);   // [bh][64][s'], key-permuted within 32-blocks
  float2* tbl = (float2*)(w + 88 * MB);   // rope table, 512 KB

  // fused cast: x + 4 weights -> bf16 (WQ/WK rows permuted per head)
  cast_all_k<<<3145728 / 256, 256, 0, stream>>>(x, WQ, WK, WV, WO, xb, wqb, wkb, wvb, wob);

  // rope cos/sin table
  rope_tbl_k<<<(SS * 32) / 256, 256, 0, stream>>>(pos, tbl);

  // fused QKV projection + in-lane RoPE(Q,K) + V-transpose (key-permuted)
  // 1D grid, XCD-chunked (T1): 8 XCD x (24 cols x 8 m-tiles), m fastest
  gemm_qkv_k<<<dim3(1536), 256, 0, stream>>>(xb, wqb, wkb, wvb, tbl, Qh, Kh, VT);

  // attention -> context (token-major); 512 perfectly-balanced blocks
  attn10_k<<<dim3(512), 512, 0, stream>>>(Qh, Kh, VT, Cb);

  // output projection (fp32 out); 1D grid, XCD-chunked (T1)
  gemm_bt_k<float><<<dim3(512), 256, 0, stream>>>(Cb, wob, out, MTOT, DM, DM);
}

// Round 9
// 230.429 us; speedup vs baseline: 1.1307x; 1.0143x over previous
//
#include <hip/hip_runtime.h>
#include <cstdint>
#include <cstddef>

#define DM 1024
#define NH 16
#define DKD 64
#define BB 4
#define SS 2048
#define MTOT (BB*SS)   // 8192 rows

typedef float  f32x4  __attribute__((ext_vector_type(4)));
typedef __bf16 bf16x8 __attribute__((ext_vector_type(8)));
typedef __bf16 bf16x4v __attribute__((ext_vector_type(4)));
typedef __bf16 bf16x2v __attribute__((ext_vector_type(2)));
using as3v = __attribute__((address_space(3))) void;
using as1v = __attribute__((address_space(1))) void;

__device__ __forceinline__ void gl2lds16(const void* g, void* l) {
  __builtin_amdgcn_global_load_lds((as1v*)g, (as3v*)l, 16, 0, 0);
}

__device__ __forceinline__ float fast_exp2(float x) {
#if __has_builtin(__builtin_amdgcn_exp2f)
  return __builtin_amdgcn_exp2f(x);
#else
  return __expf(x * 0.6931471805599453f);
#endif
}

// sin/cos with input in revolutions (v_sin_f32 semantics: D = sin(S*2pi))
__device__ __forceinline__ void sincos_rev(float rev, float* s, float* c) {
#if __has_builtin(__builtin_amdgcn_sinf) && __has_builtin(__builtin_amdgcn_cosf)
  *s = __builtin_amdgcn_sinf(rev);
  *c = __builtin_amdgcn_cosf(rev);
#else
  float a = rev * 6.283185307179586f;
  *s = __sinf(a); *c = __cosf(a);
#endif
}

// pack two f32 -> one u32 of 2 bf16 (compiler emits v_cvt_pk_bf16_f32)
__device__ __forceinline__ uint32_t pkbf(float a, float b) {
  union { uint32_t u; __bf16 h[2]; } c;
  c.h[0] = (__bf16)a; c.h[1] = (__bf16)b;
  return c.u;
}

// ---------------- fused cast fp32 -> bf16 for x + 4 weights ----------------
// WQ/WK rows are permuted per head: even feature d=2i -> i, odd d=2i+1 -> 32+i.
__global__ void cast_all_k(const float* __restrict__ x,
                           const float* __restrict__ wq, const float* __restrict__ wk,
                           const float* __restrict__ wv, const float* __restrict__ wo,
                           __bf16* __restrict__ xb,
                           __bf16* __restrict__ wqb, __bf16* __restrict__ wkb,
                           __bf16* __restrict__ wvb, __bf16* __restrict__ wob) {
  int i = blockIdx.x * blockDim.x + threadIdx.x;   // 3,145,728 float4 groups
  const float* src;
  __bf16* dst;
  int idx, oidx;
  if (i < 2097152) {          // x: 8M elems
    src = x; dst = xb; idx = i; oidx = i;
  } else {
    int j = i - 2097152;
    int w = j >> 18;          // 256K float4 per weight
    idx = j & 262143;
    src = (w == 0) ? wq : (w == 1) ? wk : (w == 2) ? wv : wo;
    dst = (w == 0) ? wqb : (w == 1) ? wkb : (w == 2) ? wvb : wob;
    if (w < 2) {
      int e = idx >> 8;            // output-feature row (1024 floats = 256 f4/row)
      int c = idx & 255;
      int d = e & 63;
      int dp = (d & 1) ? 32 + (d >> 1) : (d >> 1);
      oidx = (((e & ~63) | dp) << 8) | c;
    } else {
      oidx = idx;
    }
  }
  float4 f = ((const float4*)src)[idx];
  bf16x4v o;
  o[0] = (__bf16)f.x; o[1] = (__bf16)f.y; o[2] = (__bf16)f.z; o[3] = (__bf16)f.w;
  ((bf16x4v*)dst)[oidx] = o;
}

// ---------------- RoPE cos/sin table: tbl[s][i] = {cos,sin}(pos[s]*invf_i) --------
__global__ void rope_tbl_k(const int* __restrict__ pos, float2* __restrict__ tbl) {
  int p = blockIdx.x * blockDim.x + threadIdx.x;   // 2048*32
  int s = p >> 5;
  int i = p & 31;
  float ps = (float)pos[s];
  float invr = __expf(-0.28782313663f * (float)i) * 0.15915494309f;  // invf/(2pi)
  float rev = ps * invr;
  rev -= floorf(rev);
  float sn, cs;
  sincos_rev(rev, &sn, &cs);
  tbl[p] = make_float2(cs, sn);
}

// ======== shared GEMM K-loop pieces (v15) ========
// v13 core everywhere (BK=64, 2-phase single-barrier, XOR content swizzle,
// conflicts=0). Grid policy is per-kernel, decided by v13/v14 A/B:
//  - gemm_bt:  T1 XCD-chunked (v14 winner, ~-6us): B (wob, 2MB) is
//    L2-resident everywhere, so chunking purely dedups the 16MB A across
//    XCDs (A-fetch 8x -> 1x).
//  - gemm_qkv: v13 2D grid, col-fastest (v14's m-fastest chunking pushed the
//    per-XCD co-resident set to exactly 4MB = L2 capacity -> thrash ->
//    FETCH -38% but dur +8%; latency-bound kernels care about hit latency,
//    not bytes).

// ---------------- GEMM: C[M,N] = A[M,K] * B[N,K]^T  (token-major C) ----------------
// grid: 1D, (M/128/8 per-XCD m-tiles) x (N/128 cols) x 8 XCDs; m fastest.
template <typename CT>
__global__ __launch_bounds__(256, 2) void gemm_bt_k(const __bf16* __restrict__ A,
                                                    const __bf16* __restrict__ B,
                                                    CT* __restrict__ C,
                                                    int M, int N, int K) {
  __shared__ __bf16 As[2][128 * 64];
  __shared__ __bf16 Bs[2][128 * 64];
  const int tid  = threadIdx.x;
  const int lane = tid & 63;
  const int wid  = tid >> 6;
  const int lrow = lane & 15;
  const int quad = lane >> 4;
  const int bid  = blockIdx.x;
  const int xcd  = bid & 7;
  const int t    = bid >> 3;
  const int mpx  = (M >> 7) >> 3;          // m-tiles per XCD (8 for M=8192)
  const int col  = t / mpx;
  const int mloc = t - col * mpx;
  const int m0 = (xcd * mpx + mloc) * 128;
  const int n0 = col * 128;
  const int wm = (wid & 1) * 64;
  const int wn = (wid >> 1) * 64;

  // staging: slot s = i*256 + wid*64 + lane; row = s>>3, cl = s&7;
  // source chunk = cl ^ (row&7) = (lane&7) ^ (lane>>3)
  const int lrq  = lane >> 3;                   // 0..7
  const int srow = wid * 8 + lrq;               // row within 32-band
  const int gcol = ((lane & 7) ^ lrq) * 8;      // pre-swizzled source col
  const __bf16* Asrc = A + (size_t)(m0 + srow) * K + gcol;
  const __bf16* Bsrc = B + (size_t)(n0 + srow) * K + gcol;

  f32x4 acc[4][4] = {};

  auto stage = [&](int kt, int bsel) {
    const int k0 = kt * 64;
#pragma unroll
    for (int i = 0; i < 4; ++i)
      gl2lds16(Asrc + (size_t)(i * 32) * K + k0, &As[bsel][(i * 256 + wid * 64) * 8]);
#pragma unroll
    for (int i = 0; i < 4; ++i)
      gl2lds16(Bsrc + (size_t)(i * 32) * K + k0, &Bs[bsel][(i * 256 + wid * 64) * 8]);
  };

  stage(0, 0);
  const int kiters = K >> 6;   // 16
  for (int kk = 0; kk < kiters; ++kk) {
    __syncthreads();                 // drains prev stage (full iter to land) + publish
    if (kk + 1 < kiters) stage(kk + 1, (kk + 1) & 1);
    const __bf16* as = As[kk & 1];
    const __bf16* bs = Bs[kk & 1];
#pragma unroll
    for (int tt = 0; tt < 2; ++tt) {
      bf16x8 af[4], bfr[4];
#pragma unroll
      for (int i = 0; i < 4; ++i)
        af[i] = *(const bf16x8*)(as + (wm + i * 16 + lrow) * 64 + (((tt * 4 + quad) ^ (lrow & 7)) * 8));
#pragma unroll
      for (int i = 0; i < 4; ++i)
        bfr[i] = *(const bf16x8*)(bs + (wn + i * 16 + lrow) * 64 + (((tt * 4 + quad) ^ (lrow & 7)) * 8));
      __builtin_amdgcn_s_setprio(1);
#pragma unroll
      for (int mi = 0; mi < 4; ++mi)
#pragma unroll
        for (int ni = 0; ni < 4; ++ni)
          acc[mi][ni] = __builtin_amdgcn_mfma_f32_16x16x32_bf16(af[mi], bfr[ni], acc[mi][ni], 0, 0, 0);
      __builtin_amdgcn_s_setprio(0);
    }
  }

#pragma unroll
  for (int mi = 0; mi < 4; ++mi)
#pragma unroll
    for (int ni = 0; ni < 4; ++ni)
#pragma unroll
      for (int r = 0; r < 4; ++r) {
        int row = m0 + wm + mi * 16 + quad * 4 + r;
        int col2 = n0 + wn + ni * 16 + lrow;
        C[(size_t)row * N + col2] = (CT)acc[mi][ni][r];
      }
}

// ---------------- fused QKV GEMM + RoPE(Q,K, in-lane) + V-transpose ----------------
// V-store note (v9): VT's key axis is permuted within each 32-token block:
// position 8*quad + 4*(mi&1) + r  <-  original key (mi&1)*16 + quad*4 + r.
// This makes the attention PV A-fragment a direct pack of each lane's own
// QK^T outputs. Softmax is key-order invariant; causal mask untouched.
// grid: 2D dim3(24, 64) — v13's measured-best mapping (x = col fastest).
__global__ __launch_bounds__(256, 2) void gemm_qkv_k(const __bf16* __restrict__ A,
                                                     const __bf16* __restrict__ Bq,
                                                     const __bf16* __restrict__ Bk,
                                                     const __bf16* __restrict__ Bv,
                                                     const float2* __restrict__ tbl,
                                                     __bf16* __restrict__ Cq,
                                                     __bf16* __restrict__ Ck,
                                                     __bf16* __restrict__ Cv) {
  __shared__ __bf16 As[2][128 * 64];
  __shared__ __bf16 Bs[2][128 * 64];
  const int sel = blockIdx.x >> 3;
  const __bf16* B = sel == 0 ? Bq : sel == 1 ? Bk : Bv;
  const int n0 = (blockIdx.x & 7) * 128;
  const int m0 = blockIdx.y * 128;
  const int K = DM;
  const int tid  = threadIdx.x;
  const int lane = tid & 63;
  const int wid  = tid >> 6;
  const int lrow = lane & 15;
  const int quad = lane >> 4;
  const int wm = (wid & 1) * 64;
  const int wn = (wid >> 1) * 64;

  const int lrq  = lane >> 3;
  const int srow = wid * 8 + lrq;
  const int gcol = ((lane & 7) ^ lrq) * 8;
  const __bf16* Asrc = A + (size_t)(m0 + srow) * K + gcol;
  const __bf16* Bsrc = B + (size_t)(n0 + srow) * K + gcol;

  f32x4 acc[4][4] = {};

  auto stage = [&](int kt, int bsel) {
    const int k0 = kt * 64;
#pragma unroll
    for (int i = 0; i < 4; ++i)
      gl2lds16(Asrc + (size_t)(i * 32) * K + k0, &As[bsel][(i * 256 + wid * 64) * 8]);
#pragma unroll
    for (int i = 0; i < 4; ++i)
      gl2lds16(Bsrc + (size_t)(i * 32) * K + k0, &Bs[bsel][(i * 256 + wid * 64) * 8]);
  };

  stage(0, 0);
  const int kiters = K >> 6;   // 16
  for (int kk = 0; kk < kiters; ++kk) {
    __syncthreads();
    if (kk + 1 < kiters) stage(kk + 1, (kk + 1) & 1);
    const __bf16* as = As[kk & 1];
    const __bf16* bs = Bs[kk & 1];
#pragma unroll
    for (int tt = 0; tt < 2; ++tt) {
      bf16x8 af[4], bfr[4];
#pragma unroll
      for (int i = 0; i < 4; ++i)
        af[i] = *(const bf16x8*)(as + (wm + i * 16 + lrow) * 64 + (((tt * 4 + quad) ^ (lrow & 7)) * 8));
#pragma unroll
      for (int i = 0; i < 4; ++i)
        bfr[i] = *(const bf16x8*)(bs + (wn + i * 16 + lrow) * 64 + (((tt * 4 + quad) ^ (lrow & 7)) * 8));
      __builtin_amdgcn_s_setprio(1);
#pragma unroll
      for (int mi = 0; mi < 4; ++mi)
#pragma unroll
        for (int ni = 0; ni < 4; ++ni)
          acc[mi][ni] = __builtin_amdgcn_mfma_f32_16x16x32_bf16(af[mi], bfr[ni], acc[mi][ni], 0, 0, 0);
      __builtin_amdgcn_s_setprio(0);
    }
  }

  const int hbase = (n0 + wn) >> 6;   // head index for this wave's 64-col block
  const int bq = m0 >> 11;            // batch (128-row tile never crosses batch)

  if (sel == 2) {
    // V: store transposed into VT [bh][64][s'], s' = within-32-block permuted key
    __bf16* vt = Cv + ((size_t)(bq * NH + hbase)) * (DKD * SS);
    const int S0 = (m0 + wm) & (SS - 1);          // multiple of 64
#pragma unroll
    for (int ni = 0; ni < 4; ++ni) {
      const int d = ni * 16 + lrow;
#pragma unroll
      for (int mi = 0; mi < 4; ++mi) {
        bf16x4v pk;
#pragma unroll
        for (int r = 0; r < 4; ++r) pk[r] = (__bf16)acc[mi][ni][r];
        const int sp = S0 + (mi >> 1) * 32 + quad * 8 + (mi & 1) * 4;  // permuted pos
        *(bf16x4v*)(vt + (size_t)d * SS + sp) = pk;
      }
    }
  } else {
    // Q or K: in-lane RoPE via table. Pair = (acc[.][ni], acc[.][ni+2]), i = ni*16+lrow.
    __bf16* C = ((sel == 0) ? Cq : Ck) + ((size_t)(bq * NH + hbase)) * (SS * DKD);
#pragma unroll
    for (int ni = 0; ni < 2; ++ni) {
      const int i = ni * 16 + lrow;                 // pair index 0..31
#pragma unroll
      for (int mi = 0; mi < 4; ++mi) {
#pragma unroll
        for (int r = 0; r < 4; ++r) {
          int s = (m0 + wm + mi * 16 + quad * 4 + r) & (SS - 1);
          float2 cssn = tbl[s * 32 + i];
          float a = acc[mi][ni][r];       // x1 (even feature of the pair)
          float b = acc[mi][ni + 2][r];   // x2 (odd feature)
          C[(size_t)s * DKD + i]      = (__bf16)fmaf(a, cssn.x, -(b * cssn.y)); // x1 c - x2 s
          C[(size_t)s * DKD + 32 + i] = (__bf16)fmaf(a, cssn.y,  (b * cssn.x)); // x1 s + x2 c
        }
      }
    }
  }
}

// ---------------- attention v10: paired q-tiles, perfectly balanced blocks ----------
//  One block = q-tile pair (pr, 15-pr) -> every block runs EXACTLY 17 key-tile
//  iterations; 512 blocks = 2/CU, single round, zero tail. Double-buffer
//  pipeline carries across the segment boundary.
__global__ __launch_bounds__(512, 4) void attn10_k(const __bf16* __restrict__ Qh,
                                                   const __bf16* __restrict__ Kh,
                                                   const __bf16* __restrict__ VT,
                                                   __bf16* __restrict__ O) {
  __shared__ __bf16 Ks[2][128 * 64];   // swizzled [key][chunk8], double-buffered
  __shared__ __bf16 Vt[2][64 * 128];   // swizzled [dk][chunk8 of 16], double-buffered
  const int tid  = threadIdx.x;
  const int lane = tid & 63;
  const int wid  = tid >> 6;           // 0..7
  const int lrow = lane & 15;
  const int quad = lane >> 4;
  const int j   = blockIdx.x;          // 0..511
  const int xcd = j & 7;
  const int t   = j >> 3;              // 0..63
  const int bh  = (xcd << 3) | (t >> 3);
  const int pr  = t & 7;
  const int qa  = pr;                  // segment-0 q-tile (qa+1 key-tiles)
  const int qb  = 15 - pr;             // segment-1 q-tile (16-pr key-tiles); total 17
  const int na  = qa + 1;
  const int b  = bh >> 4;
  const int h  = bh & 15;
  const size_t hb = (size_t)bh * (SS * DKD);

  const int skr = lane >> 3;   // K staging: row-local 0..7
  const int skc = lane & 7;    //            chunk 0..7
  const int svd = lane >> 4;   // V staging: dk-local 0..3
  const int svc = lane & 15;   //            chunk 0..15

  auto stage = [&](int kt, int bsel) {
#pragma unroll
    for (int ii = 0; ii < 2; ++ii) {
      int i = wid * 2 + ii;          // 0..15
      int key = i * 8 + skr;
      int gc = skc ^ (key & 7);
      gl2lds16(Kh + hb + (size_t)(kt * 128 + key) * DKD + gc * 8, &Ks[bsel][i * 512]);
      int dk = i * 4 + svd;
      int gc2 = (svc & 8) | ((svc ^ dk) & 7);
      gl2lds16(VT + hb + (size_t)dk * SS + kt * 128 + gc2 * 8, &Vt[bsel][i * 512]);
    }
  };

  // prologue: key-tile 0 (segment 0) in flight
  stage(0, 0);
  int it = 0;   // global iteration index 0..16; LDS buffer parity = it & 1

  for (int seg = 0; seg < 2; ++seg) {
    const int qi  = seg ? qb : qa;
    const int q0  = qi * 128;
    const int nkt = qi + 1;
    const int qg  = q0 + wid * 16 + lrow;  // this lane's q-row (col of S^T)

    bf16x8 qf0, qf1;
    {
      const __bf16* qp = Qh + hb + (size_t)qg * DKD + quad * 8;
      qf0 = *(const bf16x8*)qp;
      qf1 = *(const bf16x8*)(qp + 32);
    }
    f32x4 Oa[4] = {};
    float la = 0.f, lb = 0.f;   // split l-chain (serial fp adds not reassociable)

    for (int kt = 0; kt < nkt; ++kt, ++it) {
      __syncthreads();
      {
        int nit = it + 1;
        if (nit < 17) {
          int nk = (nit < na) ? nit : (nit - na);   // next key-tile (crosses segs)
          stage(nk, nit & 1);
        }
      }
      const __bf16* ks = Ks[it & 1];
      const __bf16* vt = Vt[it & 1];

      // S^T = K * Q^T : A = K-frag (m=key), B = Q-frag (n=q)
      f32x4 sa[8];
#pragma unroll
      for (int mi = 0; mi < 8; ++mi) sa[mi] = (f32x4){0.f, 0.f, 0.f, 0.f};
      __builtin_amdgcn_s_setprio(1);
#pragma unroll
      for (int tt = 0; tt < 2; ++tt) {
        bf16x8 qf = tt ? qf1 : qf0;
#pragma unroll
        for (int mi = 0; mi < 8; ++mi) {
          bf16x8 kf = *(const bf16x8*)(ks + (mi * 16 + lrow) * 64 + (((tt * 4 + quad) ^ (lrow & 7)) * 8));
          sa[mi] = __builtin_amdgcn_mfma_f32_16x16x32_bf16(kf, qf, sa[mi], 0, 0, 0);
        }
      }
      __builtin_amdgcn_s_setprio(0);

      // fused softmax + direct pack + PV, per 32-key block kc.
      const bool lastt = (kt == nkt - 1);
#pragma unroll
      for (int kc = 0; kc < 4; ++kc) {
        union { uint32_t u[4]; bf16x8 v; } P;
#pragma unroll
        for (int half = 0; half < 2; ++half) {
          const int mi = kc * 2 + half;
          float pr4[4];
#pragma unroll
          for (int r = 0; r < 4; ++r) {
            float p = fast_exp2(sa[mi][r] * 0.18033688f - 8.0f);
            if (lastt) {
              int key = kt * 128 + kc * 32 + half * 16 + quad * 4 + r;
              p = (key <= qg) ? p : 0.f;
            }
            pr4[r] = p;
          }
          float s01 = pr4[0] + pr4[1];
          float s23 = pr4[2] + pr4[3];
          if (half) lb += (s01 + s23); else la += (s01 + s23);
          P.u[half * 2]     = pkbf(pr4[0], pr4[1]);
          P.u[half * 2 + 1] = pkbf(pr4[2], pr4[3]);
        }
        __builtin_amdgcn_s_setprio(1);
#pragma unroll
        for (int ni = 0; ni < 4; ++ni) {
          int c = kc * 4 + quad;
          int cp = (c & 8) | ((c ^ (lrow & 7)) & 7);
          bf16x8 vf = *(const bf16x8*)(vt + (ni * 16 + lrow) * 128 + cp * 8);
          Oa[ni] = __builtin_amdgcn_mfma_f32_16x16x32_bf16(P.v, vf, Oa[ni], 0, 0, 0);
        }
        __builtin_amdgcn_s_setprio(0);
      }
    }

    // per-segment epilogue: l reduction across quads, normalize, store
    float l = la + lb;
    l += __shfl_xor(l, 16, 64);
    l += __shfl_xor(l, 32, 64);
#pragma unroll
    for (int r = 0; r < 4; ++r) {
      float li = __shfl(l, quad * 4 + r, 64);   // l for q-row quad*4+r
      float inv = 1.0f / li;
      int row = q0 + wid * 16 + quad * 4 + r;
#pragma unroll
      for (int ni = 0; ni < 4; ++ni)
        O[(size_t)b * SS * DM + (size_t)row * DM + h * DKD + ni * 16 + lrow] =
            (__bf16)(Oa[ni][r] * inv);
    }
  }
}

// ---------------- launch ----------------
extern "C" void kernel_launch(void* const* d_in, const int* in_sizes, int n_in,
                              void* d_out, int out_size, void* d_ws, size_t ws_size,
                              hipStream_t stream) {
  (void)in_sizes; (void)n_in; (void)out_size; (void)ws_size;
  const float* x  = (const float*)d_in[0];
  const int*   pos = (const int*)d_in[1];
  const float* WQ = (const float*)d_in[2];
  const float* WK = (const float*)d_in[3];
  const float* WV = (const float*)d_in[4];
  const float* WO = (const float*)d_in[5];
  float* out = (float*)d_out;

  char* w = (char*)d_ws;
  const size_t MB = 1024 * 1024;
  __bf16* xb  = (__bf16*)(w);             // 16 MB
  __bf16* wqb = (__bf16*)(w + 16 * MB);   // permuted rows
  __bf16* wkb = (__bf16*)(w + 18 * MB);   // permuted rows
  __bf16* wvb = (__bf16*)(w + 20 * MB);
  __bf16* wob = (__bf16*)(w + 22 * MB);
  __bf16* Qh  = (__bf16*)(w + 24 * MB);   // head-major [bh][s][64], RoPE'd (permuted d)
  __bf16* Kh  = (__bf16*)(w + 40 * MB);   // head-major [bh][s][64], RoPE'd (permuted d)
  __bf16* Cb  = (__bf16*)(w + 56 * MB);   // context token-major
  __bf16* VT  = (__bf16*)(w + 72 * MB);   // [bh][64][s'], key-permuted within 32-blocks
  float2* tbl = (float2*)(w + 88 * MB);   // rope table, 512 KB

  // fused cast: x + 4 weights -> bf16 (WQ/WK rows permuted per head)
  cast_all_k<<<3145728 / 256, 256, 0, stream>>>(x, WQ, WK, WV, WO, xb, wqb, wkb, wvb, wob);

  // rope cos/sin table
  rope_tbl_k<<<(SS * 32) / 256, 256, 0, stream>>>(pos, tbl);

  // fused QKV projection + in-lane RoPE(Q,K) + V-transpose (key-permuted)
  // v13 2D grid (measured best for qkv)
  gemm_qkv_k<<<dim3(24, MTOT / 128), 256, 0, stream>>>(xb, wqb, wkb, wvb, tbl, Qh, Kh, VT);

  // attention -> context (token-major); 512 perfectly-balanced blocks
  attn10_k<<<dim3(512), 512, 0, stream>>>(Qh, Kh, VT, Cb);

  // output projection (fp32 out); 1D grid, XCD-chunked (T1, measured best for bt)
  gemm_bt_k<float><<<dim3(512), 256, 0, stream>>>(Cb, wob, out, MTOT, DM, DM);
}